// Round 8
// baseline (316.710 us; speedup 1.0000x reference)
//
#include <hip/hip_runtime.h>
#include <hip/hip_bf16.h>
#include <math.h>

typedef __hip_bfloat16 hbf;
typedef __attribute__((ext_vector_type(8))) short short8;
typedef __attribute__((ext_vector_type(4))) short short4v;
typedef __attribute__((ext_vector_type(4))) float f32x4;

#define ROWS 8192
#define SQSL 0.4246609001440095f  // sqrt(SCALE * log2(e)) folded into wq/bqk
#define COFF 24.0f                // static softmax offset (exp2 domain)

__device__ __forceinline__ short f2b(float f) {
    union { hbf h; short s; } u; u.h = __float2bfloat16(f); return u.s;
}
__device__ __forceinline__ float b2f(short s) {
    union { unsigned u; float f; } x;
    x.u = ((unsigned)(unsigned short)s) << 16; return x.f;
}

// ---------------------------------------------------------------------------
// prep: fp32->bf16 conversions (wq scaled by SQSL) + fused W1b@Wp / bias
// folding, all in one launch. Blocks 0..4607 convert; 4608..5119 wcomp;
// 5120..5121 bcomp.
// ---------------------------------------------------------------------------
__global__ __launch_bounds__(256)
void prep(const float* __restrict__ x0, const float* __restrict__ x1,
          const float* __restrict__ Wqk, const float* __restrict__ Wv,
          const float* __restrict__ Wp, const float* __restrict__ W1,
          const float* __restrict__ W2,
          const float* __restrict__ bp, const float* __restrict__ b1,
          short* __restrict__ xbf, short* __restrict__ wq,
          short* __restrict__ wv, short* __restrict__ w1,
          short* __restrict__ w2, short* __restrict__ wc,
          float* __restrict__ bc)
{
    const int bid = blockIdx.x, tid = threadIdx.x;
    if (bid < 4608) {
        const float* src; short* dst; int base; float sc = 1.f;
        if (bid < 2048)      { src = x0;  dst = xbf;              base = bid; }
        else if (bid < 4096) { src = x1;  dst = xbf + 8192 * 256; base = bid - 2048; }
        else if (bid < 4160) { src = Wqk; dst = wq; base = bid - 4096; sc = SQSL; }
        else if (bid < 4224) { src = Wv;  dst = wv; base = bid - 4160; }
        else if (bid < 4480) { src = W1;  dst = w1; base = bid - 4224; }
        else                 { src = W2;  dst = w2; base = bid - 4480; }
        int i = base * 256 + tid;
        float4 f = ((const float4*)src)[i];
        short4v s;
        s[0] = f2b(f.x * sc); s[1] = f2b(f.y * sc);
        s[2] = f2b(f.z * sc); s[3] = f2b(f.w * sc);
        *(short4v*)(dst + (size_t)i * 4) = s;
    } else if (bid < 5120) {
        // wc[n][i] = sum_k W1[n][256+k] * Wp[k][i]
        int n = bid - 4608;
        const float* wrow = W1 + (size_t)n * 512 + 256;
        float acc = 0.f;
        for (int k = 0; k < 256; ++k)
            acc += wrow[k] * Wp[(size_t)k * 256 + tid];
        wc[(size_t)n * 256 + tid] = f2b(acc);
    } else {
        // bc[n] = b1[n] + sum_k W1[n][256+k] * bp[k]
        int n = (bid - 5120) * 256 + tid;
        const float* wrow = W1 + (size_t)n * 512 + 256;
        float acc = b1[n];
        for (int k = 0; k < 256; ++k) acc += wrow[k] * bp[k];
        bc[n] = acc;
    }
}

// ---------------------------------------------------------------------------
// MFMA GEMM v6: block 128 tok x 64 wcol; 4 waves each 32 tok x 64 wcol
// (2 mi x 4 nj frags). Token operand staged in LDS; WEIGHT operand loaded
// directly global->VGPR in fragment layout (L1/L2-resident). C^T orientation.
// MODE 0: proj = xbf @ [wq;wv]^T (+SQSL*bqk | +bv) -> bf16; v-half blocks
//         also scatter V^T into vtbuf (fused vtrans).
// MODE 2: h = [xbf|mbuf] @ [w1a|wc]^T + bc -> bf16
// MODE 3: out = hbuf @ w2^T + b2 + x -> fp32
// ---------------------------------------------------------------------------
template<int MODE>
__global__ __launch_bounds__(256)
void gemm6(const short* __restrict__ A0, const short* __restrict__ A1,
           const short* __restrict__ Wa, const short* __restrict__ Wb,
           const float* __restrict__ bias0, const float* __restrict__ bias1,
           const float* __restrict__ x0, const float* __restrict__ x1,
           short* __restrict__ Cb, float* __restrict__ Cf,
           short* __restrict__ vt)
{
    constexpr int K = (MODE == 0) ? 256 : 512;
    const int col0 = blockIdx.x * 64;
    const int row0 = blockIdx.y * 128;
    const int tid = threadIdx.x;
    const int lane = tid & 63, wave = tid >> 6;
    const int ln = lane & 15, quad = lane >> 4;

    __shared__ short As[128 * 40];

    // weight base (MODE0 selects wq/wv half)
    const short* W = (MODE == 0 && col0 >= 256) ? Wb : Wa;
    const int wrow0 = (MODE == 0 && col0 >= 256) ? (col0 - 256) : col0;
    constexpr int WK = (MODE == 0) ? 256 : 512;   // stride of Wa

    // A staging: thread stages 2 short8: s = tid*2+p -> arow = s>>2, ac = s&3
    const int s0 = tid * 2;

    f32x4 acc[2][4];
    #pragma unroll
    for (int i = 0; i < 2; ++i)
        #pragma unroll
        for (int j = 0; j < 4; ++j) acc[i][j] = {0.f, 0.f, 0.f, 0.f};

    auto aload = [&](int p, int k0) -> short8 {
        int s = s0 + p, arow = s >> 2, ac = s & 3;
        int row = row0 + arow, kk = k0 + ac * 8;
        const short* ap;
        if (MODE == 2) ap = (kk < 256) ? A0 + (size_t)row * 256 + kk
                                       : A1 + (size_t)row * 256 + (kk - 256);
        else           ap = A0 + (size_t)row * K + kk;
        return *(const short8*)ap;
    };

    short8 aR0 = aload(0, 0), aR1 = aload(1, 0);

    for (int k0 = 0; k0 < K; k0 += 32) {
        {
            int s = s0, arow = s >> 2, ac = s & 3;
            *(short8*)&As[arow * 40 + ac * 8] = aR0;
            s = s0 + 1; arow = s >> 2; ac = s & 3;
            *(short8*)&As[arow * 40 + ac * 8] = aR1;
        }
        __syncthreads();
        if (k0 + 32 < K) { aR0 = aload(0, k0 + 32); aR1 = aload(1, k0 + 32); }

        // weight frags direct from global (L2)
        short8 bf[4];
        #pragma unroll
        for (int nj = 0; nj < 4; ++nj) {
            int kk = k0 + quad * 8;
            const short* wp_;
            if (MODE == 2 && k0 >= 256)
                wp_ = Wb + (size_t)(wrow0 + nj * 16 + ln) * 256 + (kk - 256);
            else
                wp_ = W + (size_t)(wrow0 + nj * 16 + ln) * WK + kk;
            bf[nj] = *(const short8*)wp_;
        }
        short8 a[2];
        #pragma unroll
        for (int mi = 0; mi < 2; ++mi)
            a[mi] = *(const short8*)&As[(wave * 32 + mi * 16 + ln) * 40 + quad * 8];
        #pragma unroll
        for (int mi = 0; mi < 2; ++mi)
            #pragma unroll
            for (int nj = 0; nj < 4; ++nj)
                acc[mi][nj] = __builtin_amdgcn_mfma_f32_16x16x32_bf16(
                                  bf[nj], a[mi], acc[mi][nj], 0, 0, 0);
        __syncthreads();
    }

    // epilogue: frag(mi,nj): col(ln)=tok, row(quad*4+r)=wcol
    #pragma unroll
    for (int nj = 0; nj < 4; ++nj) {
        int wrel = nj * 16 + quad * 4;
        int wcol = col0 + wrel;
        const float* bias = (MODE == 0 && col0 >= 256) ? bias1 : bias0;
        int boff = (MODE == 0 && col0 >= 256) ? (wcol - 256) : wcol;
        float4 bb = *(const float4*)(bias + boff);
        #pragma unroll
        for (int mi = 0; mi < 2; ++mi) {
            int tok = row0 + wave * 32 + mi * 16 + ln;
            f32x4 v = acc[mi][nj];
            if (MODE == 0) {
                short4v o;
                if (col0 < 256) {
                    o[0] = f2b(fmaf(bb.x, SQSL, v[0])); o[1] = f2b(fmaf(bb.y, SQSL, v[1]));
                    o[2] = f2b(fmaf(bb.z, SQSL, v[2])); o[3] = f2b(fmaf(bb.w, SQSL, v[3]));
                } else {
                    o[0] = f2b(v[0] + bb.x); o[1] = f2b(v[1] + bb.y);
                    o[2] = f2b(v[2] + bb.z); o[3] = f2b(v[3] + bb.w);
                }
                *(short4v*)(Cb + (size_t)tok * 512 + wcol) = o;
                if (col0 >= 256) {   // fused vtrans scatter
                    int g  = row0 >> 11;
                    int hh = (col0 - 256) >> 6;
                    int dd = ((col0 - 256) & 63) + wrel;
                    int tk = (row0 & 2047) + wave * 32 + mi * 16 + ln;
                    #pragma unroll
                    for (int r = 0; r < 4; ++r)
                        vt[(size_t)((g * 4 + hh) * 64 + dd + r) * 2048 + tk] = o[r];
                }
            } else if (MODE == 2) {
                short4v o;
                o[0] = f2b(v[0] + bb.x); o[1] = f2b(v[1] + bb.y);
                o[2] = f2b(v[2] + bb.z); o[3] = f2b(v[3] + bb.w);
                *(short4v*)(Cb + (size_t)tok * 512 + wcol) = o;
            } else {
                const float* xr = (tok < ROWS ? x0 + (size_t)tok * 256
                                              : x1 + (size_t)(tok - ROWS) * 256);
                float4 rv = *(const float4*)(xr + wcol);
                float4 o;
                o.x = v[0] + bb.x + rv.x; o.y = v[1] + bb.y + rv.y;
                o.z = v[2] + bb.z + rv.z; o.w = v[3] + bb.w + rv.w;
                *(float4*)(Cf + (size_t)tok * 256 + wcol) = o;
            }
        }
    }
}

// ---------------------------------------------------------------------------
// MFMA flash cross-attention v6 — S^T, static-offset softmax, Q-tile 128
// (each wave 32 q rows = 2 q-frags): K/V frag reads + staging amortized 2x.
// P region aliases QP (each wave writes only its own 32 rows).
// ---------------------------------------------------------------------------
__global__ __launch_bounds__(256)
void attn6(const short* __restrict__ proj, const short* __restrict__ vtbuf,
           short* __restrict__ mbuf)
{
    const int qt  = blockIdx.x;            // 0..15
    const int b   = blockIdx.y >> 2, h = blockIdx.y & 3;
    const int dir = blockIdx.z;
    const int tid = threadIdx.x;
    const int lane = tid & 63, wave = tid >> 6;
    const int ln   = lane & 15, quad = lane >> 4;

    const int qbase = dir * ROWS + b * 2048;
    const int kbase = (1 - dir) * ROWS + b * 2048;
    const int vg    = ((1 - dir) * 4 + b) * 4 + h;

    __shared__ short QP[128 * 72];   // Q tile then P tile
    __shared__ short KS[64 * 72];
    __shared__ short VT[64 * 72];

    const int c = tid & 7, r0 = tid >> 3;
    #pragma unroll
    for (int g = 0; g < 4; ++g) {
        int r = r0 + g * 32;
        *(short8*)&QP[r * 72 + c * 8] =
            *(const short8*)(proj + (size_t)(qbase + qt * 128 + r) * 512 + h * 64 + c * 8);
    }
    #pragma unroll
    for (int g = 0; g < 2; ++g) {
        int r = r0 + g * 32;
        *(short8*)&KS[r * 72 + c * 8] =
            *(const short8*)(proj + (size_t)(kbase + r) * 512 + h * 64 + c * 8);
        *(short8*)&VT[r * 72 + c * 8] =
            *(const short8*)(vtbuf + (size_t)(vg * 64 + r) * 2048 + c * 8);
    }
    __syncthreads();

    short8 qf[2][2];
    #pragma unroll
    for (int mi = 0; mi < 2; ++mi)
        #pragma unroll
        for (int ks = 0; ks < 2; ++ks)
            qf[mi][ks] = *(const short8*)&QP[(wave * 32 + mi * 16 + ln) * 72
                                             + ks * 32 + quad * 8];

    f32x4 Ot[2][4];
    #pragma unroll
    for (int mi = 0; mi < 2; ++mi)
        #pragma unroll
        for (int dt = 0; dt < 4; ++dt) Ot[mi][dt] = {0.f, 0.f, 0.f, 0.f};
    float lrun[2] = {0.f, 0.f};

    for (int j0 = 0; j0 < 2048; j0 += 64) {
        short8 kreg[2], vreg[2];
        const bool more = (j0 + 64) < 2048;
        if (more) {
            #pragma unroll
            for (int g = 0; g < 2; ++g) {
                int r = r0 + g * 32;
                kreg[g] = *(const short8*)(proj + (size_t)(kbase + j0 + 64 + r) * 512
                                           + h * 64 + c * 8);
                vreg[g] = *(const short8*)(vtbuf + (size_t)(vg * 64 + r) * 2048
                                           + j0 + 64 + c * 8);
            }
        }

        // S^T = K @ Q^T  (K frags shared across both q-frags)
        f32x4 St[2][4];
        #pragma unroll
        for (int t = 0; t < 4; ++t) {
            short8 k0 = *(const short8*)&KS[(t * 16 + ln) * 72 + quad * 8];
            short8 k1 = *(const short8*)&KS[(t * 16 + ln) * 72 + 32 + quad * 8];
            #pragma unroll
            for (int mi = 0; mi < 2; ++mi) {
                f32x4 z = {0.f, 0.f, 0.f, 0.f};
                z = __builtin_amdgcn_mfma_f32_16x16x32_bf16(k0, qf[mi][0], z, 0, 0, 0);
                St[mi][t] = __builtin_amdgcn_mfma_f32_16x16x32_bf16(k1, qf[mi][1], z, 0, 0, 0);
            }
        }

        // p = exp2(St - COFF); truncation-pack; P -> own QP rows
        float ss[2] = {0.f, 0.f};
        #pragma unroll
        for (int mi = 0; mi < 2; ++mi)
            #pragma unroll
            for (int t = 0; t < 4; ++t) {
                float p0 = exp2f(St[mi][t][0] - COFF);
                float p1 = exp2f(St[mi][t][1] - COFF);
                float p2 = exp2f(St[mi][t][2] - COFF);
                float p3 = exp2f(St[mi][t][3] - COFF);
                ss[mi] += (p0 + p1) + (p2 + p3);
                unsigned d0 = (__float_as_uint(p0) >> 16) |
                              (__float_as_uint(p1) & 0xffff0000u);
                unsigned d1 = (__float_as_uint(p2) >> 16) |
                              (__float_as_uint(p3) & 0xffff0000u);
                *(int2*)&QP[(wave * 32 + mi * 16 + ln) * 72 + t * 16 + quad * 4] =
                    make_int2((int)d0, (int)d1);
            }
        #pragma unroll
        for (int mi = 0; mi < 2; ++mi) {
            float t = ss[mi];
            t += __shfl_xor(t, 16);
            t += __shfl_xor(t, 32);
            lrun[mi] += t;
        }

        // O^T += V^T @ P^T  (V frags shared across both q-frags)
        short8 pa[2][2];
        #pragma unroll
        for (int mi = 0; mi < 2; ++mi)
            #pragma unroll
            for (int ks = 0; ks < 2; ++ks)
                pa[mi][ks] = *(const short8*)&QP[(wave * 32 + mi * 16 + ln) * 72
                                                 + ks * 32 + quad * 8];
        #pragma unroll
        for (int dt = 0; dt < 4; ++dt) {
            short8 v0 = *(const short8*)&VT[(dt * 16 + ln) * 72 + quad * 8];
            short8 v1 = *(const short8*)&VT[(dt * 16 + ln) * 72 + 32 + quad * 8];
            #pragma unroll
            for (int mi = 0; mi < 2; ++mi) {
                Ot[mi][dt] = __builtin_amdgcn_mfma_f32_16x16x32_bf16(
                                 v0, pa[mi][0], Ot[mi][dt], 0, 0, 0);
                Ot[mi][dt] = __builtin_amdgcn_mfma_f32_16x16x32_bf16(
                                 v1, pa[mi][1], Ot[mi][dt], 0, 0, 0);
            }
        }
        __syncthreads();   // KS/VT reads done

        if (more) {
            #pragma unroll
            for (int g = 0; g < 2; ++g) {
                int r = r0 + g * 32;
                *(short8*)&KS[r * 72 + c * 8] = kreg[g];
                *(short8*)&VT[r * 72 + c * 8] = vreg[g];
            }
        }
        __syncthreads();   // staging visible
    }

    #pragma unroll
    for (int mi = 0; mi < 2; ++mi) {
        float li = 1.f / lrun[mi];
        int tok = qbase + qt * 128 + wave * 32 + mi * 16 + ln;
        #pragma unroll
        for (int dt = 0; dt < 4; ++dt) {
            short4v o;
            #pragma unroll
            for (int r = 0; r < 4; ++r) o[r] = f2b(Ot[mi][dt][r] * li);
            *(short4v*)(mbuf + (size_t)tok * 256 + h * 64 + dt * 16 + quad * 4) = o;
        }
    }
}

// ---------------------------------------------------------------------------
// In-place LayerNorm(512) + exact GELU on bf16 rows. One wave per row.
// ---------------------------------------------------------------------------
__global__ __launch_bounds__(256)
void ln_gelu2(short* __restrict__ h, const float* __restrict__ gamma,
              const float* __restrict__ beta)
{
    const int wave = threadIdx.x >> 6, lane = threadIdx.x & 63;
    const int row = blockIdx.x * 4 + wave;
    short* hp = h + (size_t)row * 512 + lane * 8;
    short8 sv = *(const short8*)hp;
    float v[8], s1 = 0.f, s2 = 0.f;
    #pragma unroll
    for (int i = 0; i < 8; ++i) { v[i] = b2f(sv[i]); s1 += v[i]; s2 += v[i] * v[i]; }
    #pragma unroll
    for (int off = 32; off; off >>= 1) {
        s1 += __shfl_xor(s1, off);
        s2 += __shfl_xor(s2, off);
    }
    float mean = s1 * (1.f / 512.f);
    float var  = s2 * (1.f / 512.f) - mean * mean;
    float rstd = rsqrtf(var + 1e-5f);
    #pragma unroll
    for (int i = 0; i < 8; ++i) {
        int o = lane * 8 + i;
        float y = (v[i] - mean) * rstd * gamma[o] + beta[o];
        sv[i] = f2b(0.5f * y * (1.f + erff(y * 0.70710678118654752f)));
    }
    *(short8*)hp = sv;
}

// ---------------------------------------------------------------------------
extern "C" void kernel_launch(void* const* d_in, const int* in_sizes, int n_in,
                              void* d_out, int out_size, void* d_ws, size_t ws_size,
                              hipStream_t stream)
{
    const float* x0    = (const float*)d_in[0];
    const float* x1    = (const float*)d_in[1];
    const float* Wqk   = (const float*)d_in[2];
    const float* bqk   = (const float*)d_in[3];
    const float* Wv    = (const float*)d_in[4];
    const float* bv    = (const float*)d_in[5];
    const float* Wp    = (const float*)d_in[6];
    const float* bp    = (const float*)d_in[7];
    const float* W1    = (const float*)d_in[8];
    const float* b1    = (const float*)d_in[9];
    const float* gamma = (const float*)d_in[10];
    const float* beta  = (const float*)d_in[11];
    const float* W2    = (const float*)d_in[12];
    const float* b2    = (const float*)d_in[13];
    float* out = (float*)d_out;

    char* ws = (char*)d_ws;
    const size_t MB = 1024 * 1024;
    short* xbf  = (short*)ws;                    // [16384,256]  8 MB
    short* proj = (short*)(ws + 8  * MB);        // [16384,512] 16 MB (-> hbuf)
    short* vtb  = (short*)(ws + 24 * MB);        // [32*64,2048] 8 MB
    short* mbuf = (short*)(ws + 32 * MB);        // [16384,256]  8 MB
    short* wq   = (short*)(ws + 40 * MB);
    short* wv   = wq + 65536;
    short* w1   = wv + 65536;
    short* w2   = w1 + 262144;
    short* wc   = w2 + 131072;                   // [512,256] fused W1b@Wp
    float* bc   = (float*)(wc + 131072);         // [512]
    short* hbuf = proj;                          // overlays proj (dead after attn)

    prep<<<5122, 256, 0, stream>>>(x0, x1, Wqk, Wv, Wp, W1, W2, bp, b1,
                                   xbf, wq, wv, w1, w2, wc, bc);
    gemm6<0><<<dim3(8, 128), 256, 0, stream>>>(xbf, nullptr, wq, wv, bqk, bv,
                                               nullptr, nullptr, proj, nullptr, vtb);
    attn6<<<dim3(16, 16, 2), 256, 0, stream>>>(proj, vtb, mbuf);
    gemm6<2><<<dim3(8, 128), 256, 0, stream>>>(xbf, mbuf, w1, wc, bc, nullptr,
                                               nullptr, nullptr, hbuf, nullptr, nullptr);
    ln_gelu2<<<4096, 256, 0, stream>>>(hbuf, gamma, beta);
    gemm6<3><<<dim3(4, 128), 256, 0, stream>>>(hbuf, nullptr, w2, nullptr, b2, nullptr,
                                               x0, x1, nullptr, out, nullptr);
}

// Round 9
// 272.050 us; speedup vs baseline: 1.1642x; 1.1642x over previous
//
#include <hip/hip_runtime.h>
#include <hip/hip_bf16.h>
#include <math.h>

typedef __hip_bfloat16 hbf;
typedef __attribute__((ext_vector_type(8))) short short8;
typedef __attribute__((ext_vector_type(4))) short short4v;
typedef __attribute__((ext_vector_type(4))) float f32x4;

#define ROWS 8192
#define SQSL 0.4246609001440095f  // sqrt(SCALE * log2(e)) folded into wq/bqk
#define COFF 24.0f                // static softmax offset (exp2 domain)

__device__ __forceinline__ short f2b(float f) {
    union { hbf h; short s; } u; u.h = __float2bfloat16(f); return u.s;
}
__device__ __forceinline__ float b2f(short s) {
    union { unsigned u; float f; } x;
    x.u = ((unsigned)(unsigned short)s) << 16; return x.f;
}

// ---------------------------------------------------------------------------
// prep: fp32->bf16 conversions (wq scaled by SQSL) + fused W1b@Wp / b fold.
// Blocks 0..4607 convert; 4608..5119 wcomp; 5120..5121 bcomp.
// ---------------------------------------------------------------------------
__global__ __launch_bounds__(256)
void prep(const float* __restrict__ x0, const float* __restrict__ x1,
          const float* __restrict__ Wqk, const float* __restrict__ Wv,
          const float* __restrict__ Wp, const float* __restrict__ W1,
          const float* __restrict__ W2,
          const float* __restrict__ bp, const float* __restrict__ b1,
          short* __restrict__ xbf, short* __restrict__ wq,
          short* __restrict__ wv, short* __restrict__ w1,
          short* __restrict__ w2, short* __restrict__ wc,
          float* __restrict__ bc)
{
    const int bid = blockIdx.x, tid = threadIdx.x;
    if (bid < 4608) {
        const float* src; short* dst; int base; float sc = 1.f;
        if (bid < 2048)      { src = x0;  dst = xbf;              base = bid; }
        else if (bid < 4096) { src = x1;  dst = xbf + 8192 * 256; base = bid - 2048; }
        else if (bid < 4160) { src = Wqk; dst = wq; base = bid - 4096; sc = SQSL; }
        else if (bid < 4224) { src = Wv;  dst = wv; base = bid - 4160; }
        else if (bid < 4480) { src = W1;  dst = w1; base = bid - 4224; }
        else                 { src = W2;  dst = w2; base = bid - 4480; }
        int i = base * 256 + tid;
        float4 f = ((const float4*)src)[i];
        short4v s;
        s[0] = f2b(f.x * sc); s[1] = f2b(f.y * sc);
        s[2] = f2b(f.z * sc); s[3] = f2b(f.w * sc);
        *(short4v*)(dst + (size_t)i * 4) = s;
    } else if (bid < 5120) {
        int n = bid - 4608;
        const float* wrow = W1 + (size_t)n * 512 + 256;
        float acc = 0.f;
        for (int k = 0; k < 256; ++k)
            acc += wrow[k] * Wp[(size_t)k * 256 + tid];
        wc[(size_t)n * 256 + tid] = f2b(acc);
    } else {
        int n = (bid - 5120) * 256 + tid;
        const float* wrow = W1 + (size_t)n * 512 + 256;
        float acc = b1[n];
        for (int k = 0; k < 256; ++k) acc += wrow[k] * bp[k];
        bc[n] = acc;
    }
}

// ---------------------------------------------------------------------------
// MFMA GEMM (round-7 structure): 64 tok x 128 wcol block, 4 waves x (2x4),
// BK=32, both operands through LDS, register-prefetched staging, C^T stores.
// MODE 0: qk = xbf@wq^T (+SQSL*bqk) -> qkb[tok,256];
//         v = xbf@wv^T + bv -> vbuf[tok,256]
// MODE 2: h = [xbf|mbuf] @ [w1a|wc]^T + bc -> bf16 [tok,512]
// MODE 3: out = hbuf @ w2^T + b2 + x -> fp32 [tok,256]
// ---------------------------------------------------------------------------
template<int MODE>
__global__ __launch_bounds__(256)
void gemm5(const short* __restrict__ A0, const short* __restrict__ A1,
           const short* __restrict__ Wa, const short* __restrict__ Wb,
           const float* __restrict__ bias0, const float* __restrict__ bias1,
           const float* __restrict__ x0, const float* __restrict__ x1,
           short* __restrict__ Cb, short* __restrict__ Cb2,
           float* __restrict__ Cf)
{
    constexpr int K = (MODE == 0) ? 256 : 512;
    const int col0 = blockIdx.x * 128;
    const int row0 = blockIdx.y * 64;
    const int tid = threadIdx.x;
    const int lane = tid & 63, wave = tid >> 6;
    const int ln = lane & 15, quad = lane >> 4;
    const int wm = wave & 1, wn = wave >> 1;

    __shared__ short As[64 * 40];
    __shared__ short Bs[128 * 40];

    const int ar = tid >> 2, ac = tid & 3;

    f32x4 acc[2][4];
    #pragma unroll
    for (int i = 0; i < 2; ++i)
        #pragma unroll
        for (int j = 0; j < 4; ++j) acc[i][j] = {0.f, 0.f, 0.f, 0.f};

    auto aptr = [&](int kk) -> const short* {
        int row = row0 + ar;
        if (MODE == 2) return (kk < 256) ? A0 + (size_t)row * 256 + kk
                                         : A1 + (size_t)row * 256 + (kk - 256);
        return A0 + (size_t)row * K + kk;
    };
    auto wptr = [&](int rr, int kk) -> const short* {
        int n = col0 + rr;
        if (MODE == 0) {
            if (col0 < 256) return Wa + (size_t)n * 256 + kk;
            return Wb + (size_t)(n - 256) * 256 + kk;
        } else if (MODE == 2) {
            return (kk < 256) ? Wa + (size_t)n * 512 + kk
                              : Wb + (size_t)n * 256 + (kk - 256);
        } else {
            return Wa + (size_t)n * 512 + kk;
        }
    };

    short8 aR  = *(const short8*)aptr(ac * 8);
    short8 bR0 = *(const short8*)wptr(ar, ac * 8);
    short8 bR1 = *(const short8*)wptr(ar + 64, ac * 8);

    for (int k0 = 0; k0 < K; k0 += 32) {
        *(short8*)&As[ar * 40 + ac * 8] = aR;
        *(short8*)&Bs[ar * 40 + ac * 8] = bR0;
        *(short8*)&Bs[(ar + 64) * 40 + ac * 8] = bR1;
        __syncthreads();

        if (k0 + 32 < K) {
            aR  = *(const short8*)aptr(k0 + 32 + ac * 8);
            bR0 = *(const short8*)wptr(ar, k0 + 32 + ac * 8);
            bR1 = *(const short8*)wptr(ar + 64, k0 + 32 + ac * 8);
        }

        short8 a[2], b[4];
        #pragma unroll
        for (int mi = 0; mi < 2; ++mi)
            a[mi] = *(const short8*)&As[(wm * 32 + mi * 16 + ln) * 40 + quad * 8];
        #pragma unroll
        for (int nj = 0; nj < 4; ++nj)
            b[nj] = *(const short8*)&Bs[(wn * 64 + nj * 16 + ln) * 40 + quad * 8];
        #pragma unroll
        for (int mi = 0; mi < 2; ++mi)
            #pragma unroll
            for (int nj = 0; nj < 4; ++nj)
                acc[mi][nj] = __builtin_amdgcn_mfma_f32_16x16x32_bf16(
                                  b[nj], a[mi], acc[mi][nj], 0, 0, 0);
        __syncthreads();
    }

    #pragma unroll
    for (int nj = 0; nj < 4; ++nj) {
        int wrel = wn * 64 + nj * 16 + quad * 4;
        int wcol = col0 + wrel;
        const float* bias = (MODE == 0 && wcol >= 256) ? bias1 : bias0;
        int boff = (MODE == 0 && wcol >= 256) ? (wcol - 256) : wcol;
        float4 bb = *(const float4*)(bias + boff);
        #pragma unroll
        for (int mi = 0; mi < 2; ++mi) {
            int tok = row0 + wm * 32 + mi * 16 + ln;
            f32x4 v = acc[mi][nj];
            if (MODE == 0) {
                short4v o;
                if (wcol < 256) {
                    o[0] = f2b(fmaf(bb.x, SQSL, v[0])); o[1] = f2b(fmaf(bb.y, SQSL, v[1]));
                    o[2] = f2b(fmaf(bb.z, SQSL, v[2])); o[3] = f2b(fmaf(bb.w, SQSL, v[3]));
                    *(short4v*)(Cb + (size_t)tok * 256 + wcol) = o;
                } else {
                    o[0] = f2b(v[0] + bb.x); o[1] = f2b(v[1] + bb.y);
                    o[2] = f2b(v[2] + bb.z); o[3] = f2b(v[3] + bb.w);
                    *(short4v*)(Cb2 + (size_t)tok * 256 + (wcol - 256)) = o;
                }
            } else if (MODE == 2) {
                short4v o;
                o[0] = f2b(v[0] + bb.x); o[1] = f2b(v[1] + bb.y);
                o[2] = f2b(v[2] + bb.z); o[3] = f2b(v[3] + bb.w);
                *(short4v*)(Cb + (size_t)tok * 512 + wcol) = o;
            } else {
                const float* xr = (tok < ROWS ? x0 + (size_t)tok * 256
                                              : x1 + (size_t)(tok - ROWS) * 256);
                float4 rv = *(const float4*)(xr + wcol);
                float4 o;
                o.x = v[0] + bb.x + rv.x; o.y = v[1] + bb.y + rv.y;
                o.z = v[2] + bb.z + rv.z; o.w = v[3] + bb.w + rv.w;
                *(float4*)(Cf + (size_t)tok * 256 + wcol) = o;
            }
        }
    }
}

// ---------------------------------------------------------------------------
// Build V^T from vbuf[tok,256]: vtbuf[((g*4+h)*64 + d)][tok%2048].
// ---------------------------------------------------------------------------
__global__ __launch_bounds__(256)
void vtrans(const short* __restrict__ vbuf, short* __restrict__ vtbuf)
{
    const int tt = blockIdx.x;
    const int gh = blockIdx.y;
    const int g = gh >> 2, h = gh & 3;
    const int tid = threadIdx.x;
    const int tok0 = g * 2048 + tt * 64;

    __shared__ short Ls[64 * 76];

    {
        int c4 = tid & 15, r0 = tid >> 4;
        #pragma unroll
        for (int gg = 0; gg < 4; ++gg) {
            int r = r0 + gg * 16;
            *(short4v*)&Ls[r * 76 + c4 * 4] =
                *(const short4v*)(vbuf + (size_t)(tok0 + r) * 256 + h * 64 + c4 * 4);
        }
    }
    __syncthreads();

    #pragma unroll
    for (int p = 0; p < 2; ++p) {
        int ch = tid + p * 256;
        int d = ch >> 3, cc = ch & 7;
        short8 s;
        #pragma unroll
        for (int j = 0; j < 8; ++j) s[j] = Ls[(cc * 8 + j) * 76 + d];
        *(short8*)(vtbuf + (size_t)((g * 4 + h) * 64 + d) * 2048 + tt * 64 + cc * 8) = s;
    }
}

// ---------------------------------------------------------------------------
// MFMA flash cross-attention v7 — S^T, static-offset softmax, Q-tile 128
// (K/V frags amortized over 2 q-frags), KV SPLIT 2-way (z = dir*2 + half):
// each block does KV rows [half*1024, half*1024+1024) and writes UNNORMALIZED
// bf16 partial O + fp32 partial l; partials combine by addition (no max).
// Grid 1024 blocks -> 4 blocks/CU at 36.9 KB LDS.
// ---------------------------------------------------------------------------
__global__ __launch_bounds__(256)
void attn7(const short* __restrict__ qkb, const short* __restrict__ vtbuf,
           short* __restrict__ pO0, short* __restrict__ pO1,
           float* __restrict__ l0, float* __restrict__ l1)
{
    const int qt   = blockIdx.x;            // 0..15
    const int b    = blockIdx.y >> 2, h = blockIdx.y & 3;
    const int dir  = blockIdx.z >> 1;
    const int half = blockIdx.z & 1;
    const int tid = threadIdx.x;
    const int lane = tid & 63, wave = tid >> 6;
    const int ln   = lane & 15, quad = lane >> 4;

    const int qbase = dir * ROWS + b * 2048;
    const int kbase = (1 - dir) * ROWS + b * 2048;
    const int vg    = ((1 - dir) * 4 + b) * 4 + h;
    const int jlo   = half * 1024, jhi = jlo + 1024;

    short* __restrict__ pO = half ? pO1 : pO0;
    float* __restrict__ lb = half ? l1  : l0;

    __shared__ short QP[128 * 72];   // Q tile then P tile (per-wave rows)
    __shared__ short KS[64 * 72];
    __shared__ short VT[64 * 72];

    const int c = tid & 7, r0 = tid >> 3;
    #pragma unroll
    for (int g = 0; g < 4; ++g) {
        int r = r0 + g * 32;
        *(short8*)&QP[r * 72 + c * 8] =
            *(const short8*)(qkb + (size_t)(qbase + qt * 128 + r) * 256 + h * 64 + c * 8);
    }
    #pragma unroll
    for (int g = 0; g < 2; ++g) {
        int r = r0 + g * 32;
        *(short8*)&KS[r * 72 + c * 8] =
            *(const short8*)(qkb + (size_t)(kbase + jlo + r) * 256 + h * 64 + c * 8);
        *(short8*)&VT[r * 72 + c * 8] =
            *(const short8*)(vtbuf + (size_t)(vg * 64 + r) * 2048 + jlo + c * 8);
    }
    __syncthreads();

    short8 qf[2][2];
    #pragma unroll
    for (int mi = 0; mi < 2; ++mi)
        #pragma unroll
        for (int ks = 0; ks < 2; ++ks)
            qf[mi][ks] = *(const short8*)&QP[(wave * 32 + mi * 16 + ln) * 72
                                             + ks * 32 + quad * 8];

    f32x4 Ot[2][4];
    #pragma unroll
    for (int mi = 0; mi < 2; ++mi)
        #pragma unroll
        for (int dt = 0; dt < 4; ++dt) Ot[mi][dt] = {0.f, 0.f, 0.f, 0.f};
    float lrun[2] = {0.f, 0.f};

    for (int j0 = jlo; j0 < jhi; j0 += 64) {
        short8 kreg[2], vreg[2];
        const bool more = (j0 + 64) < jhi;
        if (more) {
            #pragma unroll
            for (int g = 0; g < 2; ++g) {
                int r = r0 + g * 32;
                kreg[g] = *(const short8*)(qkb + (size_t)(kbase + j0 + 64 + r) * 256
                                           + h * 64 + c * 8);
                vreg[g] = *(const short8*)(vtbuf + (size_t)(vg * 64 + r) * 2048
                                           + j0 + 64 + c * 8);
            }
        }

        // S^T = K @ Q^T (K frags shared across both q-frags)
        f32x4 St[2][4];
        #pragma unroll
        for (int t = 0; t < 4; ++t) {
            short8 k0 = *(const short8*)&KS[(t * 16 + ln) * 72 + quad * 8];
            short8 k1 = *(const short8*)&KS[(t * 16 + ln) * 72 + 32 + quad * 8];
            #pragma unroll
            for (int mi = 0; mi < 2; ++mi) {
                f32x4 z = {0.f, 0.f, 0.f, 0.f};
                z = __builtin_amdgcn_mfma_f32_16x16x32_bf16(k0, qf[mi][0], z, 0, 0, 0);
                St[mi][t] = __builtin_amdgcn_mfma_f32_16x16x32_bf16(k1, qf[mi][1], z, 0, 0, 0);
            }
        }

        // p = exp2(St - COFF); truncation-pack; P -> own QP rows
        float ss[2] = {0.f, 0.f};
        #pragma unroll
        for (int mi = 0; mi < 2; ++mi)
            #pragma unroll
            for (int t = 0; t < 4; ++t) {
                float p0 = exp2f(St[mi][t][0] - COFF);
                float p1 = exp2f(St[mi][t][1] - COFF);
                float p2 = exp2f(St[mi][t][2] - COFF);
                float p3 = exp2f(St[mi][t][3] - COFF);
                ss[mi] += (p0 + p1) + (p2 + p3);
                unsigned d0 = (__float_as_uint(p0) >> 16) |
                              (__float_as_uint(p1) & 0xffff0000u);
                unsigned d1 = (__float_as_uint(p2) >> 16) |
                              (__float_as_uint(p3) & 0xffff0000u);
                *(int2*)&QP[(wave * 32 + mi * 16 + ln) * 72 + t * 16 + quad * 4] =
                    make_int2((int)d0, (int)d1);
            }
        #pragma unroll
        for (int mi = 0; mi < 2; ++mi) {
            float t = ss[mi];
            t += __shfl_xor(t, 16);
            t += __shfl_xor(t, 32);
            lrun[mi] += t;
        }

        // O^T += V^T @ P^T  (V frags shared across both q-frags)
        short8 pa[2][2];
        #pragma unroll
        for (int mi = 0; mi < 2; ++mi)
            #pragma unroll
            for (int ks = 0; ks < 2; ++ks)
                pa[mi][ks] = *(const short8*)&QP[(wave * 32 + mi * 16 + ln) * 72
                                                 + ks * 32 + quad * 8];
        #pragma unroll
        for (int dt = 0; dt < 4; ++dt) {
            short8 v0 = *(const short8*)&VT[(dt * 16 + ln) * 72 + quad * 8];
            short8 v1 = *(const short8*)&VT[(dt * 16 + ln) * 72 + 32 + quad * 8];
            #pragma unroll
            for (int mi = 0; mi < 2; ++mi) {
                Ot[mi][dt] = __builtin_amdgcn_mfma_f32_16x16x32_bf16(
                                 v0, pa[mi][0], Ot[mi][dt], 0, 0, 0);
                Ot[mi][dt] = __builtin_amdgcn_mfma_f32_16x16x32_bf16(
                                 v1, pa[mi][1], Ot[mi][dt], 0, 0, 0);
            }
        }
        __syncthreads();   // KS/VT reads done

        if (more) {
            #pragma unroll
            for (int g = 0; g < 2; ++g) {
                int r = r0 + g * 32;
                *(short8*)&KS[r * 72 + c * 8] = kreg[g];
                *(short8*)&VT[r * 72 + c * 8] = vreg[g];
            }
        }
        __syncthreads();   // staging visible
    }

    // store UNNORMALIZED partials (bf16) + per-row l (fp32, quad 0 lanes)
    #pragma unroll
    for (int mi = 0; mi < 2; ++mi) {
        int tok = qbase + qt * 128 + wave * 32 + mi * 16 + ln;
        if (quad == 0) lb[tok] = lrun[mi];
        #pragma unroll
        for (int dt = 0; dt < 4; ++dt) {
            short4v o;
            #pragma unroll
            for (int r = 0; r < 4; ++r) o[r] = f2b(Ot[mi][dt][r]);
            *(short4v*)(pO + (size_t)tok * 256 + h * 64 + dt * 16 + quad * 4) = o;
        }
    }
}

// ---------------------------------------------------------------------------
// reduce: mbuf = (pO0 + pO1) / (l0 + l1). In-place over pO0 (= mbuf).
// ---------------------------------------------------------------------------
__global__ __launch_bounds__(256)
void attn_reduce(short* __restrict__ pO0, const short* __restrict__ pO1,
                 const float* __restrict__ l0, const float* __restrict__ l1)
{
    int i = blockIdx.x * 256 + threadIdx.x;    // 524288 short8 chunks
    int tok = i >> 5;
    float inv = 1.f / (l0[tok] + l1[tok]);
    short8 a = *(const short8*)(pO0 + (size_t)i * 8);
    short8 b = *(const short8*)(pO1 + (size_t)i * 8);
    short8 o;
    #pragma unroll
    for (int j = 0; j < 8; ++j) o[j] = f2b((b2f(a[j]) + b2f(b[j])) * inv);
    *(short8*)(pO0 + (size_t)i * 8) = o;
}

// ---------------------------------------------------------------------------
// In-place LayerNorm(512) + exact GELU on bf16 rows. One wave per row.
// ---------------------------------------------------------------------------
__global__ __launch_bounds__(256)
void ln_gelu2(short* __restrict__ h, const float* __restrict__ gamma,
              const float* __restrict__ beta)
{
    const int wave = threadIdx.x >> 6, lane = threadIdx.x & 63;
    const int row = blockIdx.x * 4 + wave;
    short* hp = h + (size_t)row * 512 + lane * 8;
    short8 sv = *(const short8*)hp;
    float v[8], s1 = 0.f, s2 = 0.f;
    #pragma unroll
    for (int i = 0; i < 8; ++i) { v[i] = b2f(sv[i]); s1 += v[i]; s2 += v[i] * v[i]; }
    #pragma unroll
    for (int off = 32; off; off >>= 1) {
        s1 += __shfl_xor(s1, off);
        s2 += __shfl_xor(s2, off);
    }
    float mean = s1 * (1.f / 512.f);
    float var  = s2 * (1.f / 512.f) - mean * mean;
    float rstd = rsqrtf(var + 1e-5f);
    #pragma unroll
    for (int i = 0; i < 8; ++i) {
        int o = lane * 8 + i;
        float y = (v[i] - mean) * rstd * gamma[o] + beta[o];
        sv[i] = f2b(0.5f * y * (1.f + erff(y * 0.70710678118654752f)));
    }
    *(short8*)hp = sv;
}

// ---------------------------------------------------------------------------
extern "C" void kernel_launch(void* const* d_in, const int* in_sizes, int n_in,
                              void* d_out, int out_size, void* d_ws, size_t ws_size,
                              hipStream_t stream)
{
    const float* x0    = (const float*)d_in[0];
    const float* x1    = (const float*)d_in[1];
    const float* Wqk   = (const float*)d_in[2];
    const float* bqk   = (const float*)d_in[3];
    const float* Wv    = (const float*)d_in[4];
    const float* bv    = (const float*)d_in[5];
    const float* Wp    = (const float*)d_in[6];
    const float* bp    = (const float*)d_in[7];
    const float* W1    = (const float*)d_in[8];
    const float* b1    = (const float*)d_in[9];
    const float* gamma = (const float*)d_in[10];
    const float* beta  = (const float*)d_in[11];
    const float* W2    = (const float*)d_in[12];
    const float* b2    = (const float*)d_in[13];
    float* out = (float*)d_out;

    char* ws = (char*)d_ws;
    const size_t MB = 1024 * 1024;
    short* xbf  = (short*)ws;                    // [0,8)   [16384,256]
    short* qkb  = (short*)(ws + 8  * MB);        // [8,16)  qk [16384,256]
    short* vtb  = (short*)(ws + 16 * MB);        // [16,24) V^T
    short* mbuf = (short*)(ws + 24 * MB);        // [24,32) pO0 -> m
    short* pO1  = (short*)(ws + 32 * MB);        // [32,40) vbuf -> pO1
    short* vbuf = pO1;
    float* l0   = (float*)(ws + 40 * MB);        // 64 KB
    float* l1   = l0 + 16384;                    // 64 KB
    float* bc   = l1 + 16384;                    // 2 KB
    short* wq   = (short*)(bc + 512);
    short* wv   = wq + 65536;
    short* w1   = wv + 65536;
    short* w2   = w1 + 262144;
    short* wc   = w2 + 131072;
    short* hbuf = qkb;                           // [8,24) overlays qkb+vtb

    prep<<<5122, 256, 0, stream>>>(x0, x1, Wqk, Wv, Wp, W1, W2, bp, b1,
                                   xbf, wq, wv, w1, w2, wc, bc);
    gemm5<0><<<dim3(4, 256), 256, 0, stream>>>(xbf, nullptr, wq, wv, bqk, bv,
                                               nullptr, nullptr, qkb, vbuf, nullptr);
    vtrans<<<dim3(32, 32), 256, 0, stream>>>(vbuf, vtb);
    attn7<<<dim3(16, 16, 4), 256, 0, stream>>>(qkb, vtb, mbuf, pO1, l0, l1);
    attn_reduce<<<2048, 256, 0, stream>>>(mbuf, pO1, l0, l1);
    gemm5<2><<<dim3(4, 256), 256, 0, stream>>>(xbf, mbuf, w1, wc, bc, nullptr,
                                               nullptr, nullptr, hbuf, nullptr, nullptr);
    ln_gelu2<<<4096, 256, 0, stream>>>(hbuf, gamma, beta);
    gemm5<3><<<dim3(2, 256), 256, 0, stream>>>(hbuf, nullptr, w2, nullptr, b2, nullptr,
                                               x0, x1, nullptr, nullptr, out);
}

// Round 10
// 248.949 us; speedup vs baseline: 1.2722x; 1.0928x over previous
//
#include <hip/hip_runtime.h>
#include <hip/hip_bf16.h>
#include <math.h>

typedef __hip_bfloat16 hbf;
typedef __attribute__((ext_vector_type(8))) short short8;
typedef __attribute__((ext_vector_type(4))) short short4v;
typedef __attribute__((ext_vector_type(4))) float f32x4;

#define ROWS 8192
#define SQSL 0.4246609001440095f  // sqrt(SCALE * log2(e)) folded into wq/bqk
#define COFF 24.0f                // static softmax offset (exp2 domain)

__device__ __forceinline__ short f2b(float f) {
    union { hbf h; short s; } u; u.h = __float2bfloat16(f); return u.s;
}
__device__ __forceinline__ float b2f(short s) {
    union { unsigned u; float f; } x;
    x.u = ((unsigned)(unsigned short)s) << 16; return x.f;
}

// ---------------------------------------------------------------------------
// prep: fp32->bf16 conversions (wq scaled by SQSL); w1c = [W1a | W1b@Wp]
// packed [512][512]; bc = b1 + W1b@bp.
// Blocks 0..4607 convert; 4608..5119 wcomp; 5120..5121 bcomp.
// ---------------------------------------------------------------------------
__global__ __launch_bounds__(256)
void prep(const float* __restrict__ x0, const float* __restrict__ x1,
          const float* __restrict__ Wqk, const float* __restrict__ Wv,
          const float* __restrict__ Wp, const float* __restrict__ W1,
          const float* __restrict__ W2,
          const float* __restrict__ bp, const float* __restrict__ b1,
          short* __restrict__ xbf, short* __restrict__ wq,
          short* __restrict__ wv, short* __restrict__ w1c,
          short* __restrict__ w2, float* __restrict__ bc)
{
    const int bid = blockIdx.x, tid = threadIdx.x;
    if (bid < 4608) {
        if (bid >= 4224 && bid < 4480) {
            // W1 chunks: keep only cols < 256 (W1a) -> w1c[n][0:256]
            int i = (bid - 4224) * 256 + tid;      // chunk of 4 floats
            int n = i >> 7, c = (i & 127) * 4;
            if (c < 256) {
                float4 f = ((const float4*)W1)[i];
                short4v s;
                s[0] = f2b(f.x); s[1] = f2b(f.y); s[2] = f2b(f.z); s[3] = f2b(f.w);
                *(short4v*)(w1c + (size_t)n * 512 + c) = s;
            }
            return;
        }
        const float* src; short* dst; int base; float sc = 1.f;
        if (bid < 2048)      { src = x0;  dst = xbf;              base = bid; }
        else if (bid < 4096) { src = x1;  dst = xbf + 8192 * 256; base = bid - 2048; }
        else if (bid < 4160) { src = Wqk; dst = wq; base = bid - 4096; sc = SQSL; }
        else if (bid < 4224) { src = Wv;  dst = wv; base = bid - 4160; }
        else                 { src = W2;  dst = w2; base = bid - 4480; }
        int i = base * 256 + tid;
        float4 f = ((const float4*)src)[i];
        short4v s;
        s[0] = f2b(f.x * sc); s[1] = f2b(f.y * sc);
        s[2] = f2b(f.z * sc); s[3] = f2b(f.w * sc);
        *(short4v*)(dst + (size_t)i * 4) = s;
    } else if (bid < 5120) {
        int n = bid - 4608;
        const float* wrow = W1 + (size_t)n * 512 + 256;
        float acc = 0.f;
        for (int k = 0; k < 256; ++k)
            acc += wrow[k] * Wp[(size_t)k * 256 + tid];
        w1c[(size_t)n * 512 + 256 + tid] = f2b(acc);
    } else {
        int n = (bid - 5120) * 256 + tid;
        const float* wrow = W1 + (size_t)n * 512 + 256;
        float acc = b1[n];
        for (int k = 0; k < 256; ++k) acc += wrow[k] * bp[k];
        bc[n] = acc;
    }
}

// ---------------------------------------------------------------------------
// QKV GEMM (round-7 structure): 64 tok x 128 wcol block, 4 waves x (2x4),
// BK=32, LDS-staged operands, register prefetch, C^T stores.
// qk = xbf@wq^T (+SQSL*bqk) -> qkb[tok,256];  v = xbf@wv^T + bv -> vbuf.
// ---------------------------------------------------------------------------
__global__ __launch_bounds__(256)
void gemm_qkv(const short* __restrict__ A0,
              const short* __restrict__ Wa, const short* __restrict__ Wb,
              const float* __restrict__ bias0, const float* __restrict__ bias1,
              short* __restrict__ Cb, short* __restrict__ Cb2)
{
    const int col0 = blockIdx.x * 128;
    const int row0 = blockIdx.y * 64;
    const int tid = threadIdx.x;
    const int lane = tid & 63, wave = tid >> 6;
    const int ln = lane & 15, quad = lane >> 4;
    const int wm = wave & 1, wn = wave >> 1;

    __shared__ short As[64 * 40];
    __shared__ short Bs[128 * 40];

    const int ar = tid >> 2, ac = tid & 3;

    f32x4 acc[2][4];
    #pragma unroll
    for (int i = 0; i < 2; ++i)
        #pragma unroll
        for (int j = 0; j < 4; ++j) acc[i][j] = {0.f, 0.f, 0.f, 0.f};

    auto wptr = [&](int rr, int kk) -> const short* {
        int n = col0 + rr;
        if (col0 < 256) return Wa + (size_t)n * 256 + kk;
        return Wb + (size_t)(n - 256) * 256 + kk;
    };

    short8 aR  = *(const short8*)(A0 + (size_t)(row0 + ar) * 256 + ac * 8);
    short8 bR0 = *(const short8*)wptr(ar, ac * 8);
    short8 bR1 = *(const short8*)wptr(ar + 64, ac * 8);

    for (int k0 = 0; k0 < 256; k0 += 32) {
        *(short8*)&As[ar * 40 + ac * 8] = aR;
        *(short8*)&Bs[ar * 40 + ac * 8] = bR0;
        *(short8*)&Bs[(ar + 64) * 40 + ac * 8] = bR1;
        __syncthreads();

        if (k0 + 32 < 256) {
            aR  = *(const short8*)(A0 + (size_t)(row0 + ar) * 256 + k0 + 32 + ac * 8);
            bR0 = *(const short8*)wptr(ar, k0 + 32 + ac * 8);
            bR1 = *(const short8*)wptr(ar + 64, k0 + 32 + ac * 8);
        }

        short8 a[2], b[4];
        #pragma unroll
        for (int mi = 0; mi < 2; ++mi)
            a[mi] = *(const short8*)&As[(wm * 32 + mi * 16 + ln) * 40 + quad * 8];
        #pragma unroll
        for (int nj = 0; nj < 4; ++nj)
            b[nj] = *(const short8*)&Bs[(wn * 64 + nj * 16 + ln) * 40 + quad * 8];
        #pragma unroll
        for (int mi = 0; mi < 2; ++mi)
            #pragma unroll
            for (int nj = 0; nj < 4; ++nj)
                acc[mi][nj] = __builtin_amdgcn_mfma_f32_16x16x32_bf16(
                                  b[nj], a[mi], acc[mi][nj], 0, 0, 0);
        __syncthreads();
    }

    #pragma unroll
    for (int nj = 0; nj < 4; ++nj) {
        int wrel = wn * 64 + nj * 16 + quad * 4;
        int wcol = col0 + wrel;
        const float* bias = (wcol >= 256) ? bias1 : bias0;
        int boff = (wcol >= 256) ? (wcol - 256) : wcol;
        float4 bb = *(const float4*)(bias + boff);
        #pragma unroll
        for (int mi = 0; mi < 2; ++mi) {
            int tok = row0 + wm * 32 + mi * 16 + ln;
            f32x4 v = acc[mi][nj];
            short4v o;
            if (wcol < 256) {
                o[0] = f2b(fmaf(bb.x, SQSL, v[0])); o[1] = f2b(fmaf(bb.y, SQSL, v[1]));
                o[2] = f2b(fmaf(bb.z, SQSL, v[2])); o[3] = f2b(fmaf(bb.w, SQSL, v[3]));
                *(short4v*)(Cb + (size_t)tok * 256 + wcol) = o;
            } else {
                o[0] = f2b(v[0] + bb.x); o[1] = f2b(v[1] + bb.y);
                o[2] = f2b(v[2] + bb.z); o[3] = f2b(v[3] + bb.w);
                *(short4v*)(Cb2 + (size_t)tok * 256 + (wcol - 256)) = o;
            }
        }
    }
}

// ---------------------------------------------------------------------------
// Build V^T from vbuf[tok,256]: vtbuf[((g*4+h)*64 + d)][tok%2048].
// ---------------------------------------------------------------------------
__global__ __launch_bounds__(256)
void vtrans(const short* __restrict__ vbuf, short* __restrict__ vtbuf)
{
    const int tt = blockIdx.x;
    const int gh = blockIdx.y;
    const int g = gh >> 2, h = gh & 3;
    const int tid = threadIdx.x;
    const int tok0 = g * 2048 + tt * 64;

    __shared__ short Ls[64 * 76];

    {
        int c4 = tid & 15, r0 = tid >> 4;
        #pragma unroll
        for (int gg = 0; gg < 4; ++gg) {
            int r = r0 + gg * 16;
            *(short4v*)&Ls[r * 76 + c4 * 4] =
                *(const short4v*)(vbuf + (size_t)(tok0 + r) * 256 + h * 64 + c4 * 4);
        }
    }
    __syncthreads();

    #pragma unroll
    for (int p = 0; p < 2; ++p) {
        int ch = tid + p * 256;
        int d = ch >> 3, cc = ch & 7;
        short8 s;
        #pragma unroll
        for (int j = 0; j < 8; ++j) s[j] = Ls[(cc * 8 + j) * 76 + d];
        *(short8*)(vtbuf + (size_t)((g * 4 + h) * 64 + d) * 2048 + tt * 64 + cc * 8) = s;
    }
}

// ---------------------------------------------------------------------------
// MFMA flash cross-attention (round-9, unchanged): S^T, static-offset
// softmax, Q-tile 128, KV split 2-way, unnormalized bf16 partials + fp32 l.
// ---------------------------------------------------------------------------
__global__ __launch_bounds__(256)
void attn7(const short* __restrict__ qkb, const short* __restrict__ vtbuf,
           short* __restrict__ pO0, short* __restrict__ pO1,
           float* __restrict__ l0, float* __restrict__ l1)
{
    const int qt   = blockIdx.x;
    const int b    = blockIdx.y >> 2, h = blockIdx.y & 3;
    const int dir  = blockIdx.z >> 1;
    const int half = blockIdx.z & 1;
    const int tid = threadIdx.x;
    const int lane = tid & 63, wave = tid >> 6;
    const int ln   = lane & 15, quad = lane >> 4;

    const int qbase = dir * ROWS + b * 2048;
    const int kbase = (1 - dir) * ROWS + b * 2048;
    const int vg    = ((1 - dir) * 4 + b) * 4 + h;
    const int jlo   = half * 1024, jhi = jlo + 1024;

    short* __restrict__ pO = half ? pO1 : pO0;
    float* __restrict__ lb = half ? l1  : l0;

    __shared__ short QP[128 * 72];
    __shared__ short KS[64 * 72];
    __shared__ short VT[64 * 72];

    const int c = tid & 7, r0 = tid >> 3;
    #pragma unroll
    for (int g = 0; g < 4; ++g) {
        int r = r0 + g * 32;
        *(short8*)&QP[r * 72 + c * 8] =
            *(const short8*)(qkb + (size_t)(qbase + qt * 128 + r) * 256 + h * 64 + c * 8);
    }
    #pragma unroll
    for (int g = 0; g < 2; ++g) {
        int r = r0 + g * 32;
        *(short8*)&KS[r * 72 + c * 8] =
            *(const short8*)(qkb + (size_t)(kbase + jlo + r) * 256 + h * 64 + c * 8);
        *(short8*)&VT[r * 72 + c * 8] =
            *(const short8*)(vtbuf + (size_t)(vg * 64 + r) * 2048 + jlo + c * 8);
    }
    __syncthreads();

    short8 qf[2][2];
    #pragma unroll
    for (int mi = 0; mi < 2; ++mi)
        #pragma unroll
        for (int ks = 0; ks < 2; ++ks)
            qf[mi][ks] = *(const short8*)&QP[(wave * 32 + mi * 16 + ln) * 72
                                             + ks * 32 + quad * 8];

    f32x4 Ot[2][4];
    #pragma unroll
    for (int mi = 0; mi < 2; ++mi)
        #pragma unroll
        for (int dt = 0; dt < 4; ++dt) Ot[mi][dt] = {0.f, 0.f, 0.f, 0.f};
    float lrun[2] = {0.f, 0.f};

    for (int j0 = jlo; j0 < jhi; j0 += 64) {
        short8 kreg[2], vreg[2];
        const bool more = (j0 + 64) < jhi;
        if (more) {
            #pragma unroll
            for (int g = 0; g < 2; ++g) {
                int r = r0 + g * 32;
                kreg[g] = *(const short8*)(qkb + (size_t)(kbase + j0 + 64 + r) * 256
                                           + h * 64 + c * 8);
                vreg[g] = *(const short8*)(vtbuf + (size_t)(vg * 64 + r) * 2048
                                           + j0 + 64 + c * 8);
            }
        }

        f32x4 St[2][4];
        #pragma unroll
        for (int t = 0; t < 4; ++t) {
            short8 k0 = *(const short8*)&KS[(t * 16 + ln) * 72 + quad * 8];
            short8 k1 = *(const short8*)&KS[(t * 16 + ln) * 72 + 32 + quad * 8];
            #pragma unroll
            for (int mi = 0; mi < 2; ++mi) {
                f32x4 z = {0.f, 0.f, 0.f, 0.f};
                z = __builtin_amdgcn_mfma_f32_16x16x32_bf16(k0, qf[mi][0], z, 0, 0, 0);
                St[mi][t] = __builtin_amdgcn_mfma_f32_16x16x32_bf16(k1, qf[mi][1], z, 0, 0, 0);
            }
        }

        float ss[2] = {0.f, 0.f};
        #pragma unroll
        for (int mi = 0; mi < 2; ++mi)
            #pragma unroll
            for (int t = 0; t < 4; ++t) {
                float p0 = exp2f(St[mi][t][0] - COFF);
                float p1 = exp2f(St[mi][t][1] - COFF);
                float p2 = exp2f(St[mi][t][2] - COFF);
                float p3 = exp2f(St[mi][t][3] - COFF);
                ss[mi] += (p0 + p1) + (p2 + p3);
                unsigned d0 = (__float_as_uint(p0) >> 16) |
                              (__float_as_uint(p1) & 0xffff0000u);
                unsigned d1 = (__float_as_uint(p2) >> 16) |
                              (__float_as_uint(p3) & 0xffff0000u);
                *(int2*)&QP[(wave * 32 + mi * 16 + ln) * 72 + t * 16 + quad * 4] =
                    make_int2((int)d0, (int)d1);
            }
        #pragma unroll
        for (int mi = 0; mi < 2; ++mi) {
            float t = ss[mi];
            t += __shfl_xor(t, 16);
            t += __shfl_xor(t, 32);
            lrun[mi] += t;
        }

        short8 pa[2][2];
        #pragma unroll
        for (int mi = 0; mi < 2; ++mi)
            #pragma unroll
            for (int ks = 0; ks < 2; ++ks)
                pa[mi][ks] = *(const short8*)&QP[(wave * 32 + mi * 16 + ln) * 72
                                                 + ks * 32 + quad * 8];
        #pragma unroll
        for (int dt = 0; dt < 4; ++dt) {
            short8 v0 = *(const short8*)&VT[(dt * 16 + ln) * 72 + quad * 8];
            short8 v1 = *(const short8*)&VT[(dt * 16 + ln) * 72 + 32 + quad * 8];
            #pragma unroll
            for (int mi = 0; mi < 2; ++mi) {
                Ot[mi][dt] = __builtin_amdgcn_mfma_f32_16x16x32_bf16(
                                 v0, pa[mi][0], Ot[mi][dt], 0, 0, 0);
                Ot[mi][dt] = __builtin_amdgcn_mfma_f32_16x16x32_bf16(
                                 v1, pa[mi][1], Ot[mi][dt], 0, 0, 0);
            }
        }
        __syncthreads();

        if (more) {
            #pragma unroll
            for (int g = 0; g < 2; ++g) {
                int r = r0 + g * 32;
                *(short8*)&KS[r * 72 + c * 8] = kreg[g];
                *(short8*)&VT[r * 72 + c * 8] = vreg[g];
            }
        }
        __syncthreads();
    }

    #pragma unroll
    for (int mi = 0; mi < 2; ++mi) {
        int tok = qbase + qt * 128 + wave * 32 + mi * 16 + ln;
        if (quad == 0) lb[tok] = lrun[mi];
        #pragma unroll
        for (int dt = 0; dt < 4; ++dt) {
            short4v o;
            #pragma unroll
            for (int r = 0; r < 4; ++r) o[r] = f2b(Ot[mi][dt][r]);
            *(short4v*)(pO + (size_t)tok * 256 + h * 64 + dt * 16 + quad * 4) = o;
        }
    }
}

// ---------------------------------------------------------------------------
// reduce: mbuf = (pO0 + pO1) / (l0 + l1), in place over pO0.
// ---------------------------------------------------------------------------
__global__ __launch_bounds__(256)
void attn_reduce(short* __restrict__ pO0, const short* __restrict__ pO1,
                 const float* __restrict__ l0, const float* __restrict__ l1)
{
    int i = blockIdx.x * 256 + threadIdx.x;
    int tok = i >> 5;
    float inv = 1.f / (l0[tok] + l1[tok]);
    short8 a = *(const short8*)(pO0 + (size_t)i * 8);
    short8 b = *(const short8*)(pO1 + (size_t)i * 8);
    short8 o;
    #pragma unroll
    for (int j = 0; j < 8; ++j) o[j] = f2b((b2f(a[j]) + b2f(b[j])) * inv);
    *(short8*)(pO0 + (size_t)i * 8) = o;
}

// ---------------------------------------------------------------------------
// Fused MLP: h = [x|m]@w1c^T + bc -> LayerNorm -> GELU -> out = h@w2^T+b2+x.
// Block = 32 tokens x full 512 h-cols (LN block-local). 4 waves x 128 hcols.
// Phase 1: K=512 loop, BK=32, W staged in 2 half-passes (Bs 256x40 = 20 KB).
// LN: quad shuffles + cross-wave stats in LDS. GELU in-reg -> H (32x520 LDS).
// Phase 2: out GEMM, w2 staged in Bs, H frags read direct from LDS.
// LDS total ~58 KB -> 2 blocks/CU, grid 512 = exactly resident.
// ---------------------------------------------------------------------------
__global__ __launch_bounds__(256)
void mlp_fused(const short* __restrict__ xbf, const short* __restrict__ mbuf,
               const short* __restrict__ w1c, const short* __restrict__ w2,
               const float* __restrict__ bc, const float* __restrict__ gamma,
               const float* __restrict__ beta, const float* __restrict__ b2,
               const float* __restrict__ x0, const float* __restrict__ x1,
               float* __restrict__ out)
{
    const int tok0 = blockIdx.x * 32;
    const int tid = threadIdx.x;
    const int lane = tid & 63, wave = tid >> 6;
    const int ln = lane & 15, quad = lane >> 4;

    __shared__ short As[32 * 40];       //  2.5 KB  token tile (one BK)
    __shared__ short Bs[256 * 40];      // 20.0 KB  weight tile (half-pass / w2)
    __shared__ short H [32 * 520];      // 33.3 KB  gelu(ln(h))
    __shared__ float stats[4][2][32];   //  1.0 KB

    f32x4 acc[2][8];
    #pragma unroll
    for (int i = 0; i < 2; ++i)
        #pragma unroll
        for (int j = 0; j < 8; ++j) acc[i][j] = {0.f, 0.f, 0.f, 0.f};

    const int br = tid >> 2, bcol = tid & 3;   // staging coords

    // ---- phase 1: h = [x|m] @ w1c^T ----
    for (int k0 = 0; k0 < 512; k0 += 32) {
        #pragma unroll
        for (int p = 0; p < 2; ++p) {
            if (p == 0 && tid < 128) {
                int arow = tid >> 2, ac = tid & 3;
                int kk = k0 + ac * 8;
                const short* ap = (kk < 256)
                    ? xbf  + (size_t)(tok0 + arow) * 256 + kk
                    : mbuf + (size_t)(tok0 + arow) * 256 + (kk - 256);
                *(short8*)&As[arow * 40 + ac * 8] = *(const short8*)ap;
            }
            #pragma unroll
            for (int q = 0; q < 4; ++q) {
                int r = br + q * 64;   // 0..255 within pass
                *(short8*)&Bs[r * 40 + bcol * 8] =
                    *(const short8*)(w1c + (size_t)(p * 256 + r) * 512 + k0 + bcol * 8);
            }
            __syncthreads();

            short8 a0 = *(const short8*)&As[ln * 40 + quad * 8];
            short8 a1 = *(const short8*)&As[(16 + ln) * 40 + quad * 8];
            #pragma unroll
            for (int nj = 0; nj < 4; ++nj) {
                short8 bf = *(const short8*)&Bs[(wave * 64 + nj * 16 + ln) * 40 + quad * 8];
                acc[0][p * 4 + nj] = __builtin_amdgcn_mfma_f32_16x16x32_bf16(
                                         bf, a0, acc[0][p * 4 + nj], 0, 0, 0);
                acc[1][p * 4 + nj] = __builtin_amdgcn_mfma_f32_16x16x32_bf16(
                                         bf, a1, acc[1][p * 4 + nj], 0, 0, 0);
            }
            __syncthreads();
        }
    }

    // add bc (h-col bias) before LN stats
    #pragma unroll
    for (int p = 0; p < 2; ++p)
        #pragma unroll
        for (int nj = 0; nj < 4; ++nj) {
            int hcol = p * 256 + wave * 64 + nj * 16 + quad * 4;
            float4 bb = *(const float4*)(bc + hcol);
            acc[0][p * 4 + nj][0] += bb.x; acc[1][p * 4 + nj][0] += bb.x;
            acc[0][p * 4 + nj][1] += bb.y; acc[1][p * 4 + nj][1] += bb.y;
            acc[0][p * 4 + nj][2] += bb.z; acc[1][p * 4 + nj][2] += bb.z;
            acc[0][p * 4 + nj][3] += bb.w; acc[1][p * 4 + nj][3] += bb.w;
        }

    // ---- LayerNorm stats (this wave's 128 cols, then cross-wave) ----
    #pragma unroll
    for (int mi = 0; mi < 2; ++mi) {
        float s1 = 0.f, s2 = 0.f;
        #pragma unroll
        for (int j = 0; j < 8; ++j)
            #pragma unroll
            for (int r = 0; r < 4; ++r) {
                float v = acc[mi][j][r];
                s1 += v; s2 += v * v;
            }
        s1 += __shfl_xor(s1, 16); s2 += __shfl_xor(s2, 16);
        s1 += __shfl_xor(s1, 32); s2 += __shfl_xor(s2, 32);
        if (quad == 0) {
            stats[wave][0][mi * 16 + ln] = s1;
            stats[wave][1][mi * 16 + ln] = s2;
        }
    }
    __syncthreads();

    float mean[2], rstd[2];
    #pragma unroll
    for (int mi = 0; mi < 2; ++mi) {
        int t = mi * 16 + ln;
        float s1 = stats[0][0][t] + stats[1][0][t] + stats[2][0][t] + stats[3][0][t];
        float s2 = stats[0][1][t] + stats[1][1][t] + stats[2][1][t] + stats[3][1][t];
        mean[mi] = s1 * (1.f / 512.f);
        float var = s2 * (1.f / 512.f) - mean[mi] * mean[mi];
        rstd[mi] = rsqrtf(var + 1e-5f);
    }

    // ---- GELU -> H ----
    #pragma unroll
    for (int p = 0; p < 2; ++p)
        #pragma unroll
        for (int nj = 0; nj < 4; ++nj) {
            int hcol = p * 256 + wave * 64 + nj * 16 + quad * 4;
            float4 gm = *(const float4*)(gamma + hcol);
            float4 bt = *(const float4*)(beta + hcol);
            #pragma unroll
            for (int mi = 0; mi < 2; ++mi) {
                short4v o;
                #pragma unroll
                for (int r = 0; r < 4; ++r) {
                    float g = (r == 0) ? gm.x : (r == 1) ? gm.y : (r == 2) ? gm.z : gm.w;
                    float bta = (r == 0) ? bt.x : (r == 1) ? bt.y : (r == 2) ? bt.z : bt.w;
                    float y = (acc[mi][p * 4 + nj][r] - mean[mi]) * rstd[mi] * g + bta;
                    o[r] = f2b(0.5f * y * (1.f + erff(y * 0.70710678118654752f)));
                }
                *(short4v*)&H[(mi * 16 + ln) * 520 + hcol] = o;
            }
        }
    __syncthreads();

    // ---- phase 2: out = H @ w2^T + b2 + x ----
    f32x4 acc2[2][4];
    #pragma unroll
    for (int i = 0; i < 2; ++i)
        #pragma unroll
        for (int j = 0; j < 4; ++j) acc2[i][j] = {0.f, 0.f, 0.f, 0.f};

    for (int k0 = 0; k0 < 512; k0 += 32) {
        #pragma unroll
        for (int q = 0; q < 4; ++q) {
            int r = br + q * 64;
            *(short8*)&Bs[r * 40 + bcol * 8] =
                *(const short8*)(w2 + (size_t)r * 512 + k0 + bcol * 8);
        }
        __syncthreads();

        short8 h0 = *(const short8*)&H[ln * 520 + k0 + quad * 8];
        short8 h1 = *(const short8*)&H[(16 + ln) * 520 + k0 + quad * 8];
        #pragma unroll
        for (int nj = 0; nj < 4; ++nj) {
            short8 wf = *(const short8*)&Bs[(wave * 64 + nj * 16 + ln) * 40 + quad * 8];
            acc2[0][nj] = __builtin_amdgcn_mfma_f32_16x16x32_bf16(wf, h0, acc2[0][nj], 0, 0, 0);
            acc2[1][nj] = __builtin_amdgcn_mfma_f32_16x16x32_bf16(wf, h1, acc2[1][nj], 0, 0, 0);
        }
        __syncthreads();
    }

    #pragma unroll
    for (int nj = 0; nj < 4; ++nj) {
        int ocol = wave * 64 + nj * 16 + quad * 4;
        float4 bb = *(const float4*)(b2 + ocol);
        #pragma unroll
        for (int mi = 0; mi < 2; ++mi) {
            int tok = tok0 + mi * 16 + ln;
            const float* xr = (tok < ROWS ? x0 + (size_t)tok * 256
                                          : x1 + (size_t)(tok - ROWS) * 256);
            float4 rv = *(const float4*)(xr + ocol);
            float4 o;
            o.x = acc2[mi][nj][0] + bb.x + rv.x;
            o.y = acc2[mi][nj][1] + bb.y + rv.y;
            o.z = acc2[mi][nj][2] + bb.z + rv.z;
            o.w = acc2[mi][nj][3] + bb.w + rv.w;
            *(float4*)(out + (size_t)tok * 256 + ocol) = o;
        }
    }
}

// ---------------------------------------------------------------------------
extern "C" void kernel_launch(void* const* d_in, const int* in_sizes, int n_in,
                              void* d_out, int out_size, void* d_ws, size_t ws_size,
                              hipStream_t stream)
{
    const float* x0    = (const float*)d_in[0];
    const float* x1    = (const float*)d_in[1];
    const float* Wqk   = (const float*)d_in[2];
    const float* bqk   = (const float*)d_in[3];
    const float* Wv    = (const float*)d_in[4];
    const float* bv    = (const float*)d_in[5];
    const float* Wp    = (const float*)d_in[6];
    const float* bp    = (const float*)d_in[7];
    const float* W1    = (const float*)d_in[8];
    const float* b1    = (const float*)d_in[9];
    const float* gamma = (const float*)d_in[10];
    const float* beta  = (const float*)d_in[11];
    const float* W2    = (const float*)d_in[12];
    const float* b2    = (const float*)d_in[13];
    float* out = (float*)d_out;

    char* ws = (char*)d_ws;
    const size_t MB = 1024 * 1024;
    short* xbf  = (short*)ws;                    // [0,8)   [16384,256]
    short* qkb  = (short*)(ws + 8  * MB);        // [8,16)
    short* vtb  = (short*)(ws + 16 * MB);        // [16,24)
    short* mbuf = (short*)(ws + 24 * MB);        // [24,32) pO0 -> m
    short* pO1  = (short*)(ws + 32 * MB);        // [32,40) vbuf -> pO1
    short* vbuf = pO1;
    float* l0   = (float*)(ws + 40 * MB);
    float* l1   = l0 + 16384;
    float* bc   = l1 + 16384;
    short* wq   = (short*)(bc + 512);
    short* wv   = wq + 65536;
    short* w1c  = wv + 65536;                    // [512,512] packed
    short* w2   = w1c + 262144;                  // [256,512]

    prep<<<5122, 256, 0, stream>>>(x0, x1, Wqk, Wv, Wp, W1, W2, bp, b1,
                                   xbf, wq, wv, w1c, w2, bc);
    gemm_qkv<<<dim3(4, 256), 256, 0, stream>>>(xbf, wq, wv, bqk, bv, qkb, vbuf);
    vtrans<<<dim3(32, 32), 256, 0, stream>>>(vbuf, vtb);
    attn7<<<dim3(16, 16, 4), 256, 0, stream>>>(qkb, vtb, mbuf, pO1, l0, l1);
    attn_reduce<<<2048, 256, 0, stream>>>(mbuf, pO1, l0, l1);
    mlp_fused<<<512, 256, 0, stream>>>(xbf, mbuf, w1c, w2, bc, gamma, beta, b2,
                                       x0, x1, out);
}

// Round 11
// 224.367 us; speedup vs baseline: 1.4116x; 1.1096x over previous
//
#include <hip/hip_runtime.h>
#include <hip/hip_bf16.h>
#include <math.h>

typedef __hip_bfloat16 hbf;
typedef __attribute__((ext_vector_type(8))) short short8;
typedef __attribute__((ext_vector_type(4))) short short4v;
typedef __attribute__((ext_vector_type(4))) float f32x4;

#define ROWS 8192
#define SQSL 0.4246609001440095f  // sqrt(SCALE * log2(e)) folded into wq/bqk
#define COFF 24.0f                // static softmax offset (exp2 domain)

__device__ __forceinline__ short f2b(float f) {
    union { hbf h; short s; } u; u.h = __float2bfloat16(f); return u.s;
}
__device__ __forceinline__ float b2f(short s) {
    union { unsigned u; float f; } x;
    x.u = ((unsigned)(unsigned short)s) << 16; return x.f;
}

// ---------------------------------------------------------------------------
// prep: fp32->bf16 conversions (wq scaled by SQSL); w1c = [W1a | W1b@Wp]
// packed [512][512]; bc = b1 + W1b@bp.
// ---------------------------------------------------------------------------
__global__ __launch_bounds__(256)
void prep(const float* __restrict__ x0, const float* __restrict__ x1,
          const float* __restrict__ Wqk, const float* __restrict__ Wv,
          const float* __restrict__ Wp, const float* __restrict__ W1,
          const float* __restrict__ W2,
          const float* __restrict__ bp, const float* __restrict__ b1,
          short* __restrict__ xbf, short* __restrict__ wq,
          short* __restrict__ wv, short* __restrict__ w1c,
          short* __restrict__ w2, float* __restrict__ bc)
{
    const int bid = blockIdx.x, tid = threadIdx.x;
    if (bid < 4608) {
        if (bid >= 4224 && bid < 4480) {
            // W1 chunks: keep only cols < 256 (W1a) -> w1c[n][0:256]
            int i = (bid - 4224) * 256 + tid;
            int n = i >> 7, c = (i & 127) * 4;
            if (c < 256) {
                float4 f = ((const float4*)W1)[i];
                short4v s;
                s[0] = f2b(f.x); s[1] = f2b(f.y); s[2] = f2b(f.z); s[3] = f2b(f.w);
                *(short4v*)(w1c + (size_t)n * 512 + c) = s;
            }
            return;
        }
        const float* src; short* dst; int base; float sc = 1.f;
        if (bid < 2048)      { src = x0;  dst = xbf;              base = bid; }
        else if (bid < 4096) { src = x1;  dst = xbf + 8192 * 256; base = bid - 2048; }
        else if (bid < 4160) { src = Wqk; dst = wq; base = bid - 4096; sc = SQSL; }
        else if (bid < 4224) { src = Wv;  dst = wv; base = bid - 4160; }
        else                 { src = W2;  dst = w2; base = bid - 4480; }
        int i = base * 256 + tid;
        float4 f = ((const float4*)src)[i];
        short4v s;
        s[0] = f2b(f.x * sc); s[1] = f2b(f.y * sc);
        s[2] = f2b(f.z * sc); s[3] = f2b(f.w * sc);
        *(short4v*)(dst + (size_t)i * 4) = s;
    } else if (bid < 5120) {
        int n = bid - 4608;
        const float* wrow = W1 + (size_t)n * 512 + 256;
        float acc = 0.f;
        for (int k = 0; k < 256; ++k)
            acc += wrow[k] * Wp[(size_t)k * 256 + tid];
        w1c[(size_t)n * 512 + 256 + tid] = f2b(acc);
    } else {
        int n = (bid - 5120) * 256 + tid;
        const float* wrow = W1 + (size_t)n * 512 + 256;
        float acc = b1[n];
        for (int k = 0; k < 256; ++k) acc += wrow[k] * bp[k];
        bc[n] = acc;
    }
}

// ---------------------------------------------------------------------------
// QKV GEMM: 64 tok x 128 wcol block, 4 waves x (2x4), BK=32, LDS-staged,
// register prefetch, C^T stores.
// ---------------------------------------------------------------------------
__global__ __launch_bounds__(256)
void gemm_qkv(const short* __restrict__ A0,
              const short* __restrict__ Wa, const short* __restrict__ Wb,
              const float* __restrict__ bias0, const float* __restrict__ bias1,
              short* __restrict__ Cb, short* __restrict__ Cb2)
{
    const int col0 = blockIdx.x * 128;
    const int row0 = blockIdx.y * 64;
    const int tid = threadIdx.x;
    const int lane = tid & 63, wave = tid >> 6;
    const int ln = lane & 15, quad = lane >> 4;
    const int wm = wave & 1, wn = wave >> 1;

    __shared__ short As[64 * 40];
    __shared__ short Bs[128 * 40];

    const int ar = tid >> 2, ac = tid & 3;

    f32x4 acc[2][4];
    #pragma unroll
    for (int i = 0; i < 2; ++i)
        #pragma unroll
        for (int j = 0; j < 4; ++j) acc[i][j] = {0.f, 0.f, 0.f, 0.f};

    auto wptr = [&](int rr, int kk) -> const short* {
        int n = col0 + rr;
        if (col0 < 256) return Wa + (size_t)n * 256 + kk;
        return Wb + (size_t)(n - 256) * 256 + kk;
    };

    short8 aR  = *(const short8*)(A0 + (size_t)(row0 + ar) * 256 + ac * 8);
    short8 bR0 = *(const short8*)wptr(ar, ac * 8);
    short8 bR1 = *(const short8*)wptr(ar + 64, ac * 8);

    for (int k0 = 0; k0 < 256; k0 += 32) {
        *(short8*)&As[ar * 40 + ac * 8] = aR;
        *(short8*)&Bs[ar * 40 + ac * 8] = bR0;
        *(short8*)&Bs[(ar + 64) * 40 + ac * 8] = bR1;
        __syncthreads();

        if (k0 + 32 < 256) {
            aR  = *(const short8*)(A0 + (size_t)(row0 + ar) * 256 + k0 + 32 + ac * 8);
            bR0 = *(const short8*)wptr(ar, k0 + 32 + ac * 8);
            bR1 = *(const short8*)wptr(ar + 64, k0 + 32 + ac * 8);
        }

        short8 a[2], b[4];
        #pragma unroll
        for (int mi = 0; mi < 2; ++mi)
            a[mi] = *(const short8*)&As[(wm * 32 + mi * 16 + ln) * 40 + quad * 8];
        #pragma unroll
        for (int nj = 0; nj < 4; ++nj)
            b[nj] = *(const short8*)&Bs[(wn * 64 + nj * 16 + ln) * 40 + quad * 8];
        #pragma unroll
        for (int mi = 0; mi < 2; ++mi)
            #pragma unroll
            for (int nj = 0; nj < 4; ++nj)
                acc[mi][nj] = __builtin_amdgcn_mfma_f32_16x16x32_bf16(
                                  b[nj], a[mi], acc[mi][nj], 0, 0, 0);
        __syncthreads();
    }

    #pragma unroll
    for (int nj = 0; nj < 4; ++nj) {
        int wrel = wn * 64 + nj * 16 + quad * 4;
        int wcol = col0 + wrel;
        const float* bias = (wcol >= 256) ? bias1 : bias0;
        int boff = (wcol >= 256) ? (wcol - 256) : wcol;
        float4 bb = *(const float4*)(bias + boff);
        #pragma unroll
        for (int mi = 0; mi < 2; ++mi) {
            int tok = row0 + wm * 32 + mi * 16 + ln;
            f32x4 v = acc[mi][nj];
            short4v o;
            if (wcol < 256) {
                o[0] = f2b(fmaf(bb.x, SQSL, v[0])); o[1] = f2b(fmaf(bb.y, SQSL, v[1]));
                o[2] = f2b(fmaf(bb.z, SQSL, v[2])); o[3] = f2b(fmaf(bb.w, SQSL, v[3]));
                *(short4v*)(Cb + (size_t)tok * 256 + wcol) = o;
            } else {
                o[0] = f2b(v[0] + bb.x); o[1] = f2b(v[1] + bb.y);
                o[2] = f2b(v[2] + bb.z); o[3] = f2b(v[3] + bb.w);
                *(short4v*)(Cb2 + (size_t)tok * 256 + (wcol - 256)) = o;
            }
        }
    }
}

// ---------------------------------------------------------------------------
// Build V^T from vbuf[tok,256]: vtbuf[((g*4+h)*64 + d)][tok%2048].
// ---------------------------------------------------------------------------
__global__ __launch_bounds__(256)
void vtrans(const short* __restrict__ vbuf, short* __restrict__ vtbuf)
{
    const int tt = blockIdx.x;
    const int gh = blockIdx.y;
    const int g = gh >> 2, h = gh & 3;
    const int tid = threadIdx.x;
    const int tok0 = g * 2048 + tt * 64;

    __shared__ short Ls[64 * 76];

    {
        int c4 = tid & 15, r0 = tid >> 4;
        #pragma unroll
        for (int gg = 0; gg < 4; ++gg) {
            int r = r0 + gg * 16;
            *(short4v*)&Ls[r * 76 + c4 * 4] =
                *(const short4v*)(vbuf + (size_t)(tok0 + r) * 256 + h * 64 + c4 * 4);
        }
    }
    __syncthreads();

    #pragma unroll
    for (int p = 0; p < 2; ++p) {
        int ch = tid + p * 256;
        int d = ch >> 3, cc = ch & 7;
        short8 s;
        #pragma unroll
        for (int j = 0; j < 8; ++j) s[j] = Ls[(cc * 8 + j) * 76 + d];
        *(short8*)(vtbuf + (size_t)((g * 4 + h) * 64 + d) * 2048 + tt * 64 + cc * 8) = s;
    }
}

// ---------------------------------------------------------------------------
// MFMA flash cross-attention: S^T, static-offset softmax (v_exp_f32 via
// builtin), Q-tile 128, KV split 2-way, unnormalized bf16 partials + fp32 l.
// ---------------------------------------------------------------------------
__global__ __launch_bounds__(256)
void attn7(const short* __restrict__ qkb, const short* __restrict__ vtbuf,
           short* __restrict__ pO0, short* __restrict__ pO1,
           float* __restrict__ l0, float* __restrict__ l1)
{
    const int qt   = blockIdx.x;
    const int b    = blockIdx.y >> 2, h = blockIdx.y & 3;
    const int dir  = blockIdx.z >> 1;
    const int half = blockIdx.z & 1;
    const int tid = threadIdx.x;
    const int lane = tid & 63, wave = tid >> 6;
    const int ln   = lane & 15, quad = lane >> 4;

    const int qbase = dir * ROWS + b * 2048;
    const int kbase = (1 - dir) * ROWS + b * 2048;
    const int vg    = ((1 - dir) * 4 + b) * 4 + h;
    const int jlo   = half * 1024, jhi = jlo + 1024;

    short* __restrict__ pO = half ? pO1 : pO0;
    float* __restrict__ lb = half ? l1  : l0;

    __shared__ short QP[128 * 72];
    __shared__ short KS[64 * 72];
    __shared__ short VT[64 * 72];

    const int c = tid & 7, r0 = tid >> 3;
    #pragma unroll
    for (int g = 0; g < 4; ++g) {
        int r = r0 + g * 32;
        *(short8*)&QP[r * 72 + c * 8] =
            *(const short8*)(qkb + (size_t)(qbase + qt * 128 + r) * 256 + h * 64 + c * 8);
    }
    #pragma unroll
    for (int g = 0; g < 2; ++g) {
        int r = r0 + g * 32;
        *(short8*)&KS[r * 72 + c * 8] =
            *(const short8*)(qkb + (size_t)(kbase + jlo + r) * 256 + h * 64 + c * 8);
        *(short8*)&VT[r * 72 + c * 8] =
            *(const short8*)(vtbuf + (size_t)(vg * 64 + r) * 2048 + jlo + c * 8);
    }
    __syncthreads();

    short8 qf[2][2];
    #pragma unroll
    for (int mi = 0; mi < 2; ++mi)
        #pragma unroll
        for (int ks = 0; ks < 2; ++ks)
            qf[mi][ks] = *(const short8*)&QP[(wave * 32 + mi * 16 + ln) * 72
                                             + ks * 32 + quad * 8];

    f32x4 Ot[2][4];
    #pragma unroll
    for (int mi = 0; mi < 2; ++mi)
        #pragma unroll
        for (int dt = 0; dt < 4; ++dt) Ot[mi][dt] = {0.f, 0.f, 0.f, 0.f};
    float lrun[2] = {0.f, 0.f};

    for (int j0 = jlo; j0 < jhi; j0 += 64) {
        short8 kreg[2], vreg[2];
        const bool more = (j0 + 64) < jhi;
        if (more) {
            #pragma unroll
            for (int g = 0; g < 2; ++g) {
                int r = r0 + g * 32;
                kreg[g] = *(const short8*)(qkb + (size_t)(kbase + j0 + 64 + r) * 256
                                           + h * 64 + c * 8);
                vreg[g] = *(const short8*)(vtbuf + (size_t)(vg * 64 + r) * 2048
                                           + j0 + 64 + c * 8);
            }
        }

        f32x4 St[2][4];
        #pragma unroll
        for (int t = 0; t < 4; ++t) {
            short8 k0 = *(const short8*)&KS[(t * 16 + ln) * 72 + quad * 8];
            short8 k1 = *(const short8*)&KS[(t * 16 + ln) * 72 + 32 + quad * 8];
            #pragma unroll
            for (int mi = 0; mi < 2; ++mi) {
                f32x4 z = {0.f, 0.f, 0.f, 0.f};
                z = __builtin_amdgcn_mfma_f32_16x16x32_bf16(k0, qf[mi][0], z, 0, 0, 0);
                St[mi][t] = __builtin_amdgcn_mfma_f32_16x16x32_bf16(k1, qf[mi][1], z, 0, 0, 0);
            }
        }

        float ss[2] = {0.f, 0.f};
        #pragma unroll
        for (int mi = 0; mi < 2; ++mi)
            #pragma unroll
            for (int t = 0; t < 4; ++t) {
                float p0 = __builtin_amdgcn_exp2f(St[mi][t][0] - COFF);
                float p1 = __builtin_amdgcn_exp2f(St[mi][t][1] - COFF);
                float p2 = __builtin_amdgcn_exp2f(St[mi][t][2] - COFF);
                float p3 = __builtin_amdgcn_exp2f(St[mi][t][3] - COFF);
                ss[mi] += (p0 + p1) + (p2 + p3);
                unsigned d0 = (__float_as_uint(p0) >> 16) |
                              (__float_as_uint(p1) & 0xffff0000u);
                unsigned d1 = (__float_as_uint(p2) >> 16) |
                              (__float_as_uint(p3) & 0xffff0000u);
                *(int2*)&QP[(wave * 32 + mi * 16 + ln) * 72 + t * 16 + quad * 4] =
                    make_int2((int)d0, (int)d1);
            }
        #pragma unroll
        for (int mi = 0; mi < 2; ++mi) {
            float t = ss[mi];
            t += __shfl_xor(t, 16);
            t += __shfl_xor(t, 32);
            lrun[mi] += t;
        }

        short8 pa[2][2];
        #pragma unroll
        for (int mi = 0; mi < 2; ++mi)
            #pragma unroll
            for (int ks = 0; ks < 2; ++ks)
                pa[mi][ks] = *(const short8*)&QP[(wave * 32 + mi * 16 + ln) * 72
                                                 + ks * 32 + quad * 8];
        #pragma unroll
        for (int dt = 0; dt < 4; ++dt) {
            short8 v0 = *(const short8*)&VT[(dt * 16 + ln) * 72 + quad * 8];
            short8 v1 = *(const short8*)&VT[(dt * 16 + ln) * 72 + 32 + quad * 8];
            #pragma unroll
            for (int mi = 0; mi < 2; ++mi) {
                Ot[mi][dt] = __builtin_amdgcn_mfma_f32_16x16x32_bf16(
                                 v0, pa[mi][0], Ot[mi][dt], 0, 0, 0);
                Ot[mi][dt] = __builtin_amdgcn_mfma_f32_16x16x32_bf16(
                                 v1, pa[mi][1], Ot[mi][dt], 0, 0, 0);
            }
        }
        __syncthreads();

        if (more) {
            #pragma unroll
            for (int g = 0; g < 2; ++g) {
                int r = r0 + g * 32;
                *(short8*)&KS[r * 72 + c * 8] = kreg[g];
                *(short8*)&VT[r * 72 + c * 8] = vreg[g];
            }
        }
        __syncthreads();
    }

    #pragma unroll
    for (int mi = 0; mi < 2; ++mi) {
        int tok = qbase + qt * 128 + wave * 32 + mi * 16 + ln;
        if (quad == 0) lb[tok] = lrun[mi];
        #pragma unroll
        for (int dt = 0; dt < 4; ++dt) {
            short4v o;
            #pragma unroll
            for (int r = 0; r < 4; ++r) o[r] = f2b(Ot[mi][dt][r]);
            *(short4v*)(pO + (size_t)tok * 256 + h * 64 + dt * 16 + quad * 4) = o;
        }
    }
}

// ---------------------------------------------------------------------------
// Fused MLP (+ fused attn reduce): m = (pO0+pO1)*rcp(l0+l1) computed in the
// A-staging of phase 1. h = [x|m]@w1c^T + bc -> LN -> GELU(tanh-cubic via
// exp2 builtin) -> out = h@w2^T + b2 + x.
// Block = 32 tokens x 512 h-cols; 4 waves x 128 hcols; LDS ~58 KB.
// ---------------------------------------------------------------------------
__global__ __launch_bounds__(256)
void mlp_fused(const short* __restrict__ xbf,
               const short* __restrict__ pO0, const short* __restrict__ pO1,
               const float* __restrict__ l0, const float* __restrict__ l1,
               const short* __restrict__ w1c, const short* __restrict__ w2,
               const float* __restrict__ bc, const float* __restrict__ gamma,
               const float* __restrict__ beta, const float* __restrict__ b2,
               const float* __restrict__ x0, const float* __restrict__ x1,
               float* __restrict__ out)
{
    const int tok0 = blockIdx.x * 32;
    const int tid = threadIdx.x;
    const int lane = tid & 63, wave = tid >> 6;
    const int ln = lane & 15, quad = lane >> 4;

    __shared__ short As[32 * 40];
    __shared__ short Bs[256 * 40];
    __shared__ short H [32 * 520];
    __shared__ float stats[4][2][32];

    f32x4 acc[2][8];
    #pragma unroll
    for (int i = 0; i < 2; ++i)
        #pragma unroll
        for (int j = 0; j < 8; ++j) acc[i][j] = {0.f, 0.f, 0.f, 0.f};

    const int br = tid >> 2, bcol = tid & 3;

    // ---- phase 1: h = [x|m] @ w1c^T ----
    for (int k0 = 0; k0 < 512; k0 += 32) {
        #pragma unroll
        for (int p = 0; p < 2; ++p) {
            if (p == 0 && tid < 128) {
                int arow = tid >> 2, ac = tid & 3;
                int kk = k0 + ac * 8;
                int tok = tok0 + arow;
                short8 s;
                if (k0 < 256) {
                    s = *(const short8*)(xbf + (size_t)tok * 256 + kk);
                } else {
                    short8 a = *(const short8*)(pO0 + (size_t)tok * 256 + (kk - 256));
                    short8 b = *(const short8*)(pO1 + (size_t)tok * 256 + (kk - 256));
                    float inv = __builtin_amdgcn_rcpf(l0[tok] + l1[tok]);
                    #pragma unroll
                    for (int j = 0; j < 8; ++j)
                        s[j] = f2b((b2f(a[j]) + b2f(b[j])) * inv);
                }
                *(short8*)&As[arow * 40 + ac * 8] = s;
            }
            #pragma unroll
            for (int q = 0; q < 4; ++q) {
                int r = br + q * 64;
                *(short8*)&Bs[r * 40 + bcol * 8] =
                    *(const short8*)(w1c + (size_t)(p * 256 + r) * 512 + k0 + bcol * 8);
            }
            __syncthreads();

            short8 a0 = *(const short8*)&As[ln * 40 + quad * 8];
            short8 a1 = *(const short8*)&As[(16 + ln) * 40 + quad * 8];
            #pragma unroll
            for (int nj = 0; nj < 4; ++nj) {
                short8 bf = *(const short8*)&Bs[(wave * 64 + nj * 16 + ln) * 40 + quad * 8];
                acc[0][p * 4 + nj] = __builtin_amdgcn_mfma_f32_16x16x32_bf16(
                                         bf, a0, acc[0][p * 4 + nj], 0, 0, 0);
                acc[1][p * 4 + nj] = __builtin_amdgcn_mfma_f32_16x16x32_bf16(
                                         bf, a1, acc[1][p * 4 + nj], 0, 0, 0);
            }
            __syncthreads();
        }
    }

    // add bc before LN stats
    #pragma unroll
    for (int p = 0; p < 2; ++p)
        #pragma unroll
        for (int nj = 0; nj < 4; ++nj) {
            int hcol = p * 256 + wave * 64 + nj * 16 + quad * 4;
            float4 bb = *(const float4*)(bc + hcol);
            acc[0][p * 4 + nj][0] += bb.x; acc[1][p * 4 + nj][0] += bb.x;
            acc[0][p * 4 + nj][1] += bb.y; acc[1][p * 4 + nj][1] += bb.y;
            acc[0][p * 4 + nj][2] += bb.z; acc[1][p * 4 + nj][2] += bb.z;
            acc[0][p * 4 + nj][3] += bb.w; acc[1][p * 4 + nj][3] += bb.w;
        }

    // ---- LayerNorm stats ----
    #pragma unroll
    for (int mi = 0; mi < 2; ++mi) {
        float s1 = 0.f, s2 = 0.f;
        #pragma unroll
        for (int j = 0; j < 8; ++j)
            #pragma unroll
            for (int r = 0; r < 4; ++r) {
                float v = acc[mi][j][r];
                s1 += v; s2 += v * v;
            }
        s1 += __shfl_xor(s1, 16); s2 += __shfl_xor(s2, 16);
        s1 += __shfl_xor(s1, 32); s2 += __shfl_xor(s2, 32);
        if (quad == 0) {
            stats[wave][0][mi * 16 + ln] = s1;
            stats[wave][1][mi * 16 + ln] = s2;
        }
    }
    __syncthreads();

    float mean[2], rstd[2];
    #pragma unroll
    for (int mi = 0; mi < 2; ++mi) {
        int t = mi * 16 + ln;
        float s1 = stats[0][0][t] + stats[1][0][t] + stats[2][0][t] + stats[3][0][t];
        float s2 = stats[0][1][t] + stats[1][1][t] + stats[2][1][t] + stats[3][1][t];
        mean[mi] = s1 * (1.f / 512.f);
        float var = s2 * (1.f / 512.f) - mean[mi] * mean[mi];
        rstd[mi] = rsqrtf(var + 1e-5f);
    }

    // ---- GELU (cubic-tanh via sigmoid identity, single v_exp_f32) -> H ----
    #pragma unroll
    for (int p = 0; p < 2; ++p)
        #pragma unroll
        for (int nj = 0; nj < 4; ++nj) {
            int hcol = p * 256 + wave * 64 + nj * 16 + quad * 4;
            float4 gm = *(const float4*)(gamma + hcol);
            float4 bt = *(const float4*)(beta + hcol);
            #pragma unroll
            for (int mi = 0; mi < 2; ++mi) {
                short4v o;
                #pragma unroll
                for (int r = 0; r < 4; ++r) {
                    float g = (r == 0) ? gm.x : (r == 1) ? gm.y : (r == 2) ? gm.z : gm.w;
                    float bta = (r == 0) ? bt.x : (r == 1) ? bt.y : (r == 2) ? bt.z : bt.w;
                    float y = (acc[mi][p * 4 + nj][r] - mean[mi]) * rstd[mi] * g + bta;
                    float u = y * fmaf(y * y, 0.0356774081f, 0.7978845608f);
                    float e = __builtin_amdgcn_exp2f(u * -2.8853900818f);
                    o[r] = f2b(y * __builtin_amdgcn_rcpf(1.f + e));
                }
                *(short4v*)&H[(mi * 16 + ln) * 520 + hcol] = o;
            }
        }
    __syncthreads();

    // ---- phase 2: out = H @ w2^T + b2 + x ----
    f32x4 acc2[2][4];
    #pragma unroll
    for (int i = 0; i < 2; ++i)
        #pragma unroll
        for (int j = 0; j < 4; ++j) acc2[i][j] = {0.f, 0.f, 0.f, 0.f};

    for (int k0 = 0; k0 < 512; k0 += 32) {
        #pragma unroll
        for (int q = 0; q < 4; ++q) {
            int r = br + q * 64;
            *(short8*)&Bs[r * 40 + bcol * 8] =
                *(const short8*)(w2 + (size_t)r * 512 + k0 + bcol * 8);
        }
        __syncthreads();

        short8 h0 = *(const short8*)&H[ln * 520 + k0 + quad * 8];
        short8 h1 = *(const short8*)&H[(16 + ln) * 520 + k0 + quad * 8];
        #pragma unroll
        for (int nj = 0; nj < 4; ++nj) {
            short8 wf = *(const short8*)&Bs[(wave * 64 + nj * 16 + ln) * 40 + quad * 8];
            acc2[0][nj] = __builtin_amdgcn_mfma_f32_16x16x32_bf16(wf, h0, acc2[0][nj], 0, 0, 0);
            acc2[1][nj] = __builtin_amdgcn_mfma_f32_16x16x32_bf16(wf, h1, acc2[1][nj], 0, 0, 0);
        }
        __syncthreads();
    }

    #pragma unroll
    for (int nj = 0; nj < 4; ++nj) {
        int ocol = wave * 64 + nj * 16 + quad * 4;
        float4 bb = *(const float4*)(b2 + ocol);
        #pragma unroll
        for (int mi = 0; mi < 2; ++mi) {
            int tok = tok0 + mi * 16 + ln;
            const float* xr = (tok < ROWS ? x0 + (size_t)tok * 256
                                          : x1 + (size_t)(tok - ROWS) * 256);
            float4 rv = *(const float4*)(xr + ocol);
            float4 o;
            o.x = acc2[mi][nj][0] + bb.x + rv.x;
            o.y = acc2[mi][nj][1] + bb.y + rv.y;
            o.z = acc2[mi][nj][2] + bb.z + rv.z;
            o.w = acc2[mi][nj][3] + bb.w + rv.w;
            *(float4*)(out + (size_t)tok * 256 + ocol) = o;
        }
    }
}

// ---------------------------------------------------------------------------
extern "C" void kernel_launch(void* const* d_in, const int* in_sizes, int n_in,
                              void* d_out, int out_size, void* d_ws, size_t ws_size,
                              hipStream_t stream)
{
    const float* x0    = (const float*)d_in[0];
    const float* x1    = (const float*)d_in[1];
    const float* Wqk   = (const float*)d_in[2];
    const float* bqk   = (const float*)d_in[3];
    const float* Wv    = (const float*)d_in[4];
    const float* bv    = (const float*)d_in[5];
    const float* Wp    = (const float*)d_in[6];
    const float* bp    = (const float*)d_in[7];
    const float* W1    = (const float*)d_in[8];
    const float* b1    = (const float*)d_in[9];
    const float* gamma = (const float*)d_in[10];
    const float* beta  = (const float*)d_in[11];
    const float* W2    = (const float*)d_in[12];
    const float* b2    = (const float*)d_in[13];
    float* out = (float*)d_out;

    char* ws = (char*)d_ws;
    const size_t MB = 1024 * 1024;
    short* xbf  = (short*)ws;                    // [0,8)
    short* qkb  = (short*)(ws + 8  * MB);        // [8,16)
    short* vtb  = (short*)(ws + 16 * MB);        // [16,24)
    short* pO0  = (short*)(ws + 24 * MB);        // [24,32)
    short* pO1  = (short*)(ws + 32 * MB);        // [32,40)  (vbuf before attn)
    short* vbuf = pO1;
    float* l0   = (float*)(ws + 40 * MB);
    float* l1   = l0 + 16384;
    float* bc   = l1 + 16384;
    short* wq   = (short*)(bc + 512);
    short* wv   = wq + 65536;
    short* w1c  = wv + 65536;                    // [512,512]
    short* w2   = w1c + 262144;                  // [256,512]

    prep<<<5122, 256, 0, stream>>>(x0, x1, Wqk, Wv, Wp, W1, W2, bp, b1,
                                   xbf, wq, wv, w1c, w2, bc);
    gemm_qkv<<<dim3(4, 256), 256, 0, stream>>>(xbf, wq, wv, bqk, bv, qkb, vbuf);
    vtrans<<<dim3(32, 32), 256, 0, stream>>>(vbuf, vtb);
    attn7<<<dim3(16, 16, 4), 256, 0, stream>>>(qkb, vtb, pO0, pO1, l0, l1);
    mlp_fused<<<512, 256, 0, stream>>>(xbf, pO0, pO1, l0, l1, w1c, w2, bc,
                                       gamma, beta, b2, x0, x1, out);
}

// Round 12
// 221.045 us; speedup vs baseline: 1.4328x; 1.0150x over previous
//
#include <hip/hip_runtime.h>
#include <hip/hip_bf16.h>
#include <math.h>

typedef __hip_bfloat16 hbf;
typedef __attribute__((ext_vector_type(8))) short short8;
typedef __attribute__((ext_vector_type(4))) short short4v;
typedef __attribute__((ext_vector_type(4))) float f32x4;

#define ROWS 8192
#define SQSL 0.4246609001440095f  // sqrt(SCALE * log2(e)) folded into wq/bqk
#define COFF 24.0f                // static softmax offset (exp2 domain)

__device__ __forceinline__ short f2b(float f) {
    union { hbf h; short s; } u; u.h = __float2bfloat16(f); return u.s;
}
__device__ __forceinline__ float b2f(short s) {
    union { unsigned u; float f; } x;
    x.u = ((unsigned)(unsigned short)s) << 16; return x.f;
}

// ---------------------------------------------------------------------------
// prep (weights only): wq*SQSL, wv, w1c=[W1a | W1b@Wp], w2, bc=b1+W1b@bp.
// bid<64 wq; <128 wv; <384 w1a; <512 w2; <1024 wcomp; else bcomp (1026 blks).
// ---------------------------------------------------------------------------
__global__ __launch_bounds__(256)
void prep(const float* __restrict__ Wqk, const float* __restrict__ Wv,
          const float* __restrict__ Wp, const float* __restrict__ W1,
          const float* __restrict__ W2,
          const float* __restrict__ bp, const float* __restrict__ b1,
          short* __restrict__ wq, short* __restrict__ wv,
          short* __restrict__ w1c, short* __restrict__ w2,
          float* __restrict__ bc)
{
    const int bid = blockIdx.x, tid = threadIdx.x;
    if (bid < 512) {
        const float* src; short* dst; int base; float sc = 1.f;
        if (bid < 64)       { src = Wqk; dst = wq; base = bid;       sc = SQSL; }
        else if (bid < 128) { src = Wv;  dst = wv; base = bid - 64; }
        else if (bid < 384) {
            // W1: keep only cols<256 (W1a) -> w1c[n][0:256]
            int i = (bid - 128) * 256 + tid;
            int n = i >> 7, c = (i & 127) * 4;
            if (c < 256) {
                float4 f = ((const float4*)W1)[i];
                short4v s;
                s[0] = f2b(f.x); s[1] = f2b(f.y); s[2] = f2b(f.z); s[3] = f2b(f.w);
                *(short4v*)(w1c + (size_t)n * 512 + c) = s;
            }
            return;
        }
        else                { src = W2;  dst = w2; base = bid - 384; }
        int i = base * 256 + tid;
        float4 f = ((const float4*)src)[i];
        short4v s;
        s[0] = f2b(f.x * sc); s[1] = f2b(f.y * sc);
        s[2] = f2b(f.z * sc); s[3] = f2b(f.w * sc);
        *(short4v*)(dst + (size_t)i * 4) = s;
    } else if (bid < 1024) {
        int n = bid - 512;
        const float* wrow = W1 + (size_t)n * 512 + 256;
        float acc = 0.f;
        for (int k = 0; k < 256; ++k)
            acc += wrow[k] * Wp[(size_t)k * 256 + tid];
        w1c[(size_t)n * 512 + 256 + tid] = f2b(acc);
    } else {
        int n = (bid - 1024) * 256 + tid;
        const float* wrow = W1 + (size_t)n * 512 + 256;
        float acc = b1[n];
        for (int k = 0; k < 256; ++k) acc += wrow[k] * bp[k];
        bc[n] = acc;
    }
}

// ---------------------------------------------------------------------------
// QKV GEMM: 64 tok x 128 wcol block, 4 waves x (2x4), BK=32. A operand read
// from fp32 x0/x1 and converted in staging (no xbf buffer). C^T stores.
// ---------------------------------------------------------------------------
__global__ __launch_bounds__(256)
void gemm_qkv(const float* __restrict__ x0, const float* __restrict__ x1,
              const short* __restrict__ Wa, const short* __restrict__ Wb,
              const float* __restrict__ bias0, const float* __restrict__ bias1,
              short* __restrict__ Cb, short* __restrict__ Cb2)
{
    const int col0 = blockIdx.x * 128;
    const int row0 = blockIdx.y * 64;
    const int tid = threadIdx.x;
    const int lane = tid & 63, wave = tid >> 6;
    const int ln = lane & 15, quad = lane >> 4;
    const int wm = wave & 1, wn = wave >> 1;

    __shared__ short As[64 * 40];
    __shared__ short Bs[128 * 40];

    const int ar = tid >> 2, ac = tid & 3;

    f32x4 acc[2][4];
    #pragma unroll
    for (int i = 0; i < 2; ++i)
        #pragma unroll
        for (int j = 0; j < 4; ++j) acc[i][j] = {0.f, 0.f, 0.f, 0.f};

    auto wptr = [&](int rr, int kk) -> const short* {
        int n = col0 + rr;
        if (col0 < 256) return Wa + (size_t)n * 256 + kk;
        return Wb + (size_t)(n - 256) * 256 + kk;
    };
    const float* xrow = (row0 + ar < ROWS)
        ? x0 + (size_t)(row0 + ar) * 256
        : x1 + (size_t)(row0 + ar - ROWS) * 256;

    float4 aF0 = ((const float4*)(xrow + ac * 8))[0];
    float4 aF1 = ((const float4*)(xrow + ac * 8))[1];
    short8 bR0 = *(const short8*)wptr(ar, ac * 8);
    short8 bR1 = *(const short8*)wptr(ar + 64, ac * 8);

    for (int k0 = 0; k0 < 256; k0 += 32) {
        {
            short8 s;
            s[0] = f2b(aF0.x); s[1] = f2b(aF0.y); s[2] = f2b(aF0.z); s[3] = f2b(aF0.w);
            s[4] = f2b(aF1.x); s[5] = f2b(aF1.y); s[6] = f2b(aF1.z); s[7] = f2b(aF1.w);
            *(short8*)&As[ar * 40 + ac * 8] = s;
        }
        *(short8*)&Bs[ar * 40 + ac * 8] = bR0;
        *(short8*)&Bs[(ar + 64) * 40 + ac * 8] = bR1;
        __syncthreads();

        if (k0 + 32 < 256) {
            aF0 = ((const float4*)(xrow + k0 + 32 + ac * 8))[0];
            aF1 = ((const float4*)(xrow + k0 + 32 + ac * 8))[1];
            bR0 = *(const short8*)wptr(ar, k0 + 32 + ac * 8);
            bR1 = *(const short8*)wptr(ar + 64, k0 + 32 + ac * 8);
        }

        short8 a[2], b[4];
        #pragma unroll
        for (int mi = 0; mi < 2; ++mi)
            a[mi] = *(const short8*)&As[(wm * 32 + mi * 16 + ln) * 40 + quad * 8];
        #pragma unroll
        for (int nj = 0; nj < 4; ++nj)
            b[nj] = *(const short8*)&Bs[(wn * 64 + nj * 16 + ln) * 40 + quad * 8];
        #pragma unroll
        for (int mi = 0; mi < 2; ++mi)
            #pragma unroll
            for (int nj = 0; nj < 4; ++nj)
                acc[mi][nj] = __builtin_amdgcn_mfma_f32_16x16x32_bf16(
                                  b[nj], a[mi], acc[mi][nj], 0, 0, 0);
        __syncthreads();
    }

    #pragma unroll
    for (int nj = 0; nj < 4; ++nj) {
        int wrel = wn * 64 + nj * 16 + quad * 4;
        int wcol = col0 + wrel;
        const float* bias = (wcol >= 256) ? bias1 : bias0;
        int boff = (wcol >= 256) ? (wcol - 256) : wcol;
        float4 bb = *(const float4*)(bias + boff);
        #pragma unroll
        for (int mi = 0; mi < 2; ++mi) {
            int tok = row0 + wm * 32 + mi * 16 + ln;
            f32x4 v = acc[mi][nj];
            short4v o;
            if (wcol < 256) {
                o[0] = f2b(fmaf(bb.x, SQSL, v[0])); o[1] = f2b(fmaf(bb.y, SQSL, v[1]));
                o[2] = f2b(fmaf(bb.z, SQSL, v[2])); o[3] = f2b(fmaf(bb.w, SQSL, v[3]));
                *(short4v*)(Cb + (size_t)tok * 256 + wcol) = o;
            } else {
                o[0] = f2b(v[0] + bb.x); o[1] = f2b(v[1] + bb.y);
                o[2] = f2b(v[2] + bb.z); o[3] = f2b(v[3] + bb.w);
                *(short4v*)(Cb2 + (size_t)tok * 256 + (wcol - 256)) = o;
            }
        }
    }
}

// ---------------------------------------------------------------------------
// Build V^T from vbuf[tok,256]: vtbuf[((g*4+h)*64 + d)][tok%2048].
// ---------------------------------------------------------------------------
__global__ __launch_bounds__(256)
void vtrans(const short* __restrict__ vbuf, short* __restrict__ vtbuf)
{
    const int tt = blockIdx.x;
    const int gh = blockIdx.y;
    const int g = gh >> 2, h = gh & 3;
    const int tid = threadIdx.x;
    const int tok0 = g * 2048 + tt * 64;

    __shared__ short Ls[64 * 76];

    {
        int c4 = tid & 15, r0 = tid >> 4;
        #pragma unroll
        for (int gg = 0; gg < 4; ++gg) {
            int r = r0 + gg * 16;
            *(short4v*)&Ls[r * 76 + c4 * 4] =
                *(const short4v*)(vbuf + (size_t)(tok0 + r) * 256 + h * 64 + c4 * 4);
        }
    }
    __syncthreads();

    #pragma unroll
    for (int p = 0; p < 2; ++p) {
        int ch = tid + p * 256;
        int d = ch >> 3, cc = ch & 7;
        short8 s;
        #pragma unroll
        for (int j = 0; j < 8; ++j) s[j] = Ls[(cc * 8 + j) * 76 + d];
        *(short8*)(vtbuf + (size_t)((g * 4 + h) * 64 + d) * 2048 + tt * 64 + cc * 8) = s;
    }
}

// ---------------------------------------------------------------------------
// MFMA flash cross-attention v8: 2 waves x 64 q-rows (K/V frag reads
// amortized 4x per wave), Q-tile 128, KV split 2-way, static-offset softmax,
// unnormalized partials. 128 threads; LDS 36.9 KB -> 4 blocks/CU.
// ---------------------------------------------------------------------------
__global__ __launch_bounds__(128, 2)
void attn8(const short* __restrict__ qkb, const short* __restrict__ vtbuf,
           short* __restrict__ pO0, short* __restrict__ pO1,
           float* __restrict__ l0, float* __restrict__ l1)
{
    const int qt   = blockIdx.x;            // 0..15
    const int b    = blockIdx.y >> 2, h = blockIdx.y & 3;
    const int dir  = blockIdx.z >> 1;
    const int half = blockIdx.z & 1;
    const int tid = threadIdx.x;
    const int lane = tid & 63, wave = tid >> 6;   // wave 0/1
    const int ln   = lane & 15, quad = lane >> 4;

    const int qbase = dir * ROWS + b * 2048;
    const int kbase = (1 - dir) * ROWS + b * 2048;
    const int vg    = ((1 - dir) * 4 + b) * 4 + h;
    const int jlo   = half * 1024, jhi = jlo + 1024;

    short* __restrict__ pO = half ? pO1 : pO0;
    float* __restrict__ lb = half ? l1  : l0;

    __shared__ short QP[128 * 72];   // Q tile then P tile (per-wave rows)
    __shared__ short KS[64 * 72];
    __shared__ short VT[64 * 72];

    const int c = tid & 7, r0 = tid >> 3;   // r0: 0..15
    #pragma unroll
    for (int g = 0; g < 8; ++g) {
        int r = r0 + g * 16;
        *(short8*)&QP[r * 72 + c * 8] =
            *(const short8*)(qkb + (size_t)(qbase + qt * 128 + r) * 256 + h * 64 + c * 8);
    }
    #pragma unroll
    for (int g = 0; g < 4; ++g) {
        int r = r0 + g * 16;
        *(short8*)&KS[r * 72 + c * 8] =
            *(const short8*)(qkb + (size_t)(kbase + jlo + r) * 256 + h * 64 + c * 8);
        *(short8*)&VT[r * 72 + c * 8] =
            *(const short8*)(vtbuf + (size_t)(vg * 64 + r) * 2048 + jlo + c * 8);
    }
    __syncthreads();

    short8 qf[4][2];
    #pragma unroll
    for (int mi = 0; mi < 4; ++mi)
        #pragma unroll
        for (int ks = 0; ks < 2; ++ks)
            qf[mi][ks] = *(const short8*)&QP[(wave * 64 + mi * 16 + ln) * 72
                                             + ks * 32 + quad * 8];

    f32x4 Ot[4][4];
    #pragma unroll
    for (int mi = 0; mi < 4; ++mi)
        #pragma unroll
        for (int dt = 0; dt < 4; ++dt) Ot[mi][dt] = {0.f, 0.f, 0.f, 0.f};
    float lrun[4] = {0.f, 0.f, 0.f, 0.f};

    for (int j0 = jlo; j0 < jhi; j0 += 64) {
        short8 kreg[4], vreg[4];
        const bool more = (j0 + 64) < jhi;
        if (more) {
            #pragma unroll
            for (int g = 0; g < 4; ++g) {
                int r = r0 + g * 16;
                kreg[g] = *(const short8*)(qkb + (size_t)(kbase + j0 + 64 + r) * 256
                                           + h * 64 + c * 8);
                vreg[g] = *(const short8*)(vtbuf + (size_t)(vg * 64 + r) * 2048
                                           + j0 + 64 + c * 8);
            }
        }

        // S^T = K @ Q^T   (K frags shared across 4 q-subtiles)
        f32x4 St[4][4];
        #pragma unroll
        for (int t = 0; t < 4; ++t) {
            short8 k0 = *(const short8*)&KS[(t * 16 + ln) * 72 + quad * 8];
            short8 k1 = *(const short8*)&KS[(t * 16 + ln) * 72 + 32 + quad * 8];
            #pragma unroll
            for (int mi = 0; mi < 4; ++mi) {
                f32x4 z = {0.f, 0.f, 0.f, 0.f};
                z = __builtin_amdgcn_mfma_f32_16x16x32_bf16(k0, qf[mi][0], z, 0, 0, 0);
                St[mi][t] = __builtin_amdgcn_mfma_f32_16x16x32_bf16(k1, qf[mi][1], z, 0, 0, 0);
            }
        }

        // p = exp2(St - COFF); truncation-pack; P -> own QP rows
        float ss[4] = {0.f, 0.f, 0.f, 0.f};
        #pragma unroll
        for (int mi = 0; mi < 4; ++mi)
            #pragma unroll
            for (int t = 0; t < 4; ++t) {
                float p0 = __builtin_amdgcn_exp2f(St[mi][t][0] - COFF);
                float p1 = __builtin_amdgcn_exp2f(St[mi][t][1] - COFF);
                float p2 = __builtin_amdgcn_exp2f(St[mi][t][2] - COFF);
                float p3 = __builtin_amdgcn_exp2f(St[mi][t][3] - COFF);
                ss[mi] += (p0 + p1) + (p2 + p3);
                unsigned d0 = (__float_as_uint(p0) >> 16) |
                              (__float_as_uint(p1) & 0xffff0000u);
                unsigned d1 = (__float_as_uint(p2) >> 16) |
                              (__float_as_uint(p3) & 0xffff0000u);
                *(int2*)&QP[(wave * 64 + mi * 16 + ln) * 72 + t * 16 + quad * 4] =
                    make_int2((int)d0, (int)d1);
            }
        #pragma unroll
        for (int mi = 0; mi < 4; ++mi) {
            float t = ss[mi];
            t += __shfl_xor(t, 16);
            t += __shfl_xor(t, 32);
            lrun[mi] += t;
        }

        // O^T += V^T @ P^T   (V frags shared across 4 q-subtiles)
        short8 pa[4][2];
        #pragma unroll
        for (int mi = 0; mi < 4; ++mi)
            #pragma unroll
            for (int ks = 0; ks < 2; ++ks)
                pa[mi][ks] = *(const short8*)&QP[(wave * 64 + mi * 16 + ln) * 72
                                                 + ks * 32 + quad * 8];
        #pragma unroll
        for (int dt = 0; dt < 4; ++dt) {
            short8 v0 = *(const short8*)&VT[(dt * 16 + ln) * 72 + quad * 8];
            short8 v1 = *(const short8*)&VT[(dt * 16 + ln) * 72 + 32 + quad * 8];
            #pragma unroll
            for (int mi = 0; mi < 4; ++mi) {
                Ot[mi][dt] = __builtin_amdgcn_mfma_f32_16x16x32_bf16(
                                 v0, pa[mi][0], Ot[mi][dt], 0, 0, 0);
                Ot[mi][dt] = __builtin_amdgcn_mfma_f32_16x16x32_bf16(
                                 v1, pa[mi][1], Ot[mi][dt], 0, 0, 0);
            }
        }
        __syncthreads();

        if (more) {
            #pragma unroll
            for (int g = 0; g < 4; ++g) {
                int r = r0 + g * 16;
                *(short8*)&KS[r * 72 + c * 8] = kreg[g];
                *(short8*)&VT[r * 72 + c * 8] = vreg[g];
            }
        }
        __syncthreads();
    }

    #pragma unroll
    for (int mi = 0; mi < 4; ++mi) {
        int tok = qbase + qt * 128 + wave * 64 + mi * 16 + ln;
        if (quad == 0) lb[tok] = lrun[mi];
        #pragma unroll
        for (int dt = 0; dt < 4; ++dt) {
            short4v o;
            #pragma unroll
            for (int r = 0; r < 4; ++r) o[r] = f2b(Ot[mi][dt][r]);
            *(short4v*)(pO + (size_t)tok * 256 + h * 64 + dt * 16 + quad * 4) = o;
        }
    }
}

// ---------------------------------------------------------------------------
// Fused MLP (+ fused attn reduce): m = (pO0+pO1)*rcp(l0+l1) in A-staging;
// x read fp32 + converted in staging. h = [x|m]@w1c^T + bc -> LN -> GELU
// (sigmoid form, raw exp2) -> out = h@w2^T + b2 + x.
// ---------------------------------------------------------------------------
__global__ __launch_bounds__(256)
void mlp_fused(const float* __restrict__ x0, const float* __restrict__ x1,
               const short* __restrict__ pO0, const short* __restrict__ pO1,
               const float* __restrict__ l0, const float* __restrict__ l1,
               const short* __restrict__ w1c, const short* __restrict__ w2,
               const float* __restrict__ bc, const float* __restrict__ gamma,
               const float* __restrict__ beta, const float* __restrict__ b2,
               float* __restrict__ out)
{
    const int tok0 = blockIdx.x * 32;
    const int tid = threadIdx.x;
    const int lane = tid & 63, wave = tid >> 6;
    const int ln = lane & 15, quad = lane >> 4;

    __shared__ short As[32 * 40];
    __shared__ short Bs[256 * 40];
    __shared__ short H [32 * 520];
    __shared__ float stats[4][2][32];

    f32x4 acc[2][8];
    #pragma unroll
    for (int i = 0; i < 2; ++i)
        #pragma unroll
        for (int j = 0; j < 8; ++j) acc[i][j] = {0.f, 0.f, 0.f, 0.f};

    const int br = tid >> 2, bcol = tid & 3;

    // ---- phase 1: h = [x|m] @ w1c^T ----
    for (int k0 = 0; k0 < 512; k0 += 32) {
        #pragma unroll
        for (int p = 0; p < 2; ++p) {
            if (p == 0 && tid < 128) {
                int arow = tid >> 2, ac = tid & 3;
                int kk = k0 + ac * 8;
                int tok = tok0 + arow;
                short8 s;
                if (k0 < 256) {
                    const float* xr = (tok < ROWS ? x0 + (size_t)tok * 256
                                                  : x1 + (size_t)(tok - ROWS) * 256) + kk;
                    float4 f0 = ((const float4*)xr)[0];
                    float4 f1 = ((const float4*)xr)[1];
                    s[0] = f2b(f0.x); s[1] = f2b(f0.y); s[2] = f2b(f0.z); s[3] = f2b(f0.w);
                    s[4] = f2b(f1.x); s[5] = f2b(f1.y); s[6] = f2b(f1.z); s[7] = f2b(f1.w);
                } else {
                    short8 a = *(const short8*)(pO0 + (size_t)tok * 256 + (kk - 256));
                    short8 b = *(const short8*)(pO1 + (size_t)tok * 256 + (kk - 256));
                    float inv = __builtin_amdgcn_rcpf(l0[tok] + l1[tok]);
                    #pragma unroll
                    for (int j = 0; j < 8; ++j)
                        s[j] = f2b((b2f(a[j]) + b2f(b[j])) * inv);
                }
                *(short8*)&As[arow * 40 + ac * 8] = s;
            }
            #pragma unroll
            for (int q = 0; q < 4; ++q) {
                int r = br + q * 64;
                *(short8*)&Bs[r * 40 + bcol * 8] =
                    *(const short8*)(w1c + (size_t)(p * 256 + r) * 512 + k0 + bcol * 8);
            }
            __syncthreads();

            short8 a0 = *(const short8*)&As[ln * 40 + quad * 8];
            short8 a1 = *(const short8*)&As[(16 + ln) * 40 + quad * 8];
            #pragma unroll
            for (int nj = 0; nj < 4; ++nj) {
                short8 bf = *(const short8*)&Bs[(wave * 64 + nj * 16 + ln) * 40 + quad * 8];
                acc[0][p * 4 + nj] = __builtin_amdgcn_mfma_f32_16x16x32_bf16(
                                         bf, a0, acc[0][p * 4 + nj], 0, 0, 0);
                acc[1][p * 4 + nj] = __builtin_amdgcn_mfma_f32_16x16x32_bf16(
                                         bf, a1, acc[1][p * 4 + nj], 0, 0, 0);
            }
            __syncthreads();
        }
    }

    // add bc before LN stats
    #pragma unroll
    for (int p = 0; p < 2; ++p)
        #pragma unroll
        for (int nj = 0; nj < 4; ++nj) {
            int hcol = p * 256 + wave * 64 + nj * 16 + quad * 4;
            float4 bb = *(const float4*)(bc + hcol);
            acc[0][p * 4 + nj][0] += bb.x; acc[1][p * 4 + nj][0] += bb.x;
            acc[0][p * 4 + nj][1] += bb.y; acc[1][p * 4 + nj][1] += bb.y;
            acc[0][p * 4 + nj][2] += bb.z; acc[1][p * 4 + nj][2] += bb.z;
            acc[0][p * 4 + nj][3] += bb.w; acc[1][p * 4 + nj][3] += bb.w;
        }

    // ---- LayerNorm stats ----
    #pragma unroll
    for (int mi = 0; mi < 2; ++mi) {
        float s1 = 0.f, s2 = 0.f;
        #pragma unroll
        for (int j = 0; j < 8; ++j)
            #pragma unroll
            for (int r = 0; r < 4; ++r) {
                float v = acc[mi][j][r];
                s1 += v; s2 += v * v;
            }
        s1 += __shfl_xor(s1, 16); s2 += __shfl_xor(s2, 16);
        s1 += __shfl_xor(s1, 32); s2 += __shfl_xor(s2, 32);
        if (quad == 0) {
            stats[wave][0][mi * 16 + ln] = s1;
            stats[wave][1][mi * 16 + ln] = s2;
        }
    }
    __syncthreads();

    float mean[2], rstd[2];
    #pragma unroll
    for (int mi = 0; mi < 2; ++mi) {
        int t = mi * 16 + ln;
        float s1 = stats[0][0][t] + stats[1][0][t] + stats[2][0][t] + stats[3][0][t];
        float s2 = stats[0][1][t] + stats[1][1][t] + stats[2][1][t] + stats[3][1][t];
        mean[mi] = s1 * (1.f / 512.f);
        float var = s2 * (1.f / 512.f) - mean[mi] * mean[mi];
        rstd[mi] = rsqrtf(var + 1e-5f);
    }

    // ---- GELU -> H ----
    #pragma unroll
    for (int p = 0; p < 2; ++p)
        #pragma unroll
        for (int nj = 0; nj < 4; ++nj) {
            int hcol = p * 256 + wave * 64 + nj * 16 + quad * 4;
            float4 gm = *(const float4*)(gamma + hcol);
            float4 bt = *(const float4*)(beta + hcol);
            #pragma unroll
            for (int mi = 0; mi < 2; ++mi) {
                short4v o;
                #pragma unroll
                for (int r = 0; r < 4; ++r) {
                    float g = (r == 0) ? gm.x : (r == 1) ? gm.y : (r == 2) ? gm.z : gm.w;
                    float bta = (r == 0) ? bt.x : (r == 1) ? bt.y : (r == 2) ? bt.z : bt.w;
                    float y = (acc[mi][p * 4 + nj][r] - mean[mi]) * rstd[mi] * g + bta;
                    float u = y * fmaf(y * y, 0.0356774081f, 0.7978845608f);
                    float e = __builtin_amdgcn_exp2f(u * -2.8853900818f);
                    o[r] = f2b(y * __builtin_amdgcn_rcpf(1.f + e));
                }
                *(short4v*)&H[(mi * 16 + ln) * 520 + hcol] = o;
            }
        }
    __syncthreads();

    // ---- phase 2: out = H @ w2^T + b2 + x ----
    f32x4 acc2[2][4];
    #pragma unroll
    for (int i = 0; i < 2; ++i)
        #pragma unroll
        for (int j = 0; j < 4; ++j) acc2[i][j] = {0.f, 0.f, 0.f, 0.f};

    for (int k0 = 0; k0 < 512; k0 += 32) {
        #pragma unroll
        for (int q = 0; q < 4; ++q) {
            int r = br + q * 64;
            *(short8*)&Bs[r * 40 + bcol * 8] =
                *(const short8*)(w2 + (size_t)r * 512 + k0 + bcol * 8);
        }
        __syncthreads();

        short8 h0 = *(const short8*)&H[ln * 520 + k0 + quad * 8];
        short8 h1 = *(const short8*)&H[(16 + ln) * 520 + k0 + quad * 8];
        #pragma unroll
        for (int nj = 0; nj < 4; ++nj) {
            short8 wf = *(const short8*)&Bs[(wave * 64 + nj * 16 + ln) * 40 + quad * 8];
            acc2[0][nj] = __builtin_amdgcn_mfma_f32_16x16x32_bf16(wf, h0, acc2[0][nj], 0, 0, 0);
            acc2[1][nj] = __builtin_amdgcn_mfma_f32_16x16x32_bf16(wf, h1, acc2[1][nj], 0, 0, 0);
        }
        __syncthreads();
    }

    #pragma unroll
    for (int nj = 0; nj < 4; ++nj) {
        int ocol = wave * 64 + nj * 16 + quad * 4;
        float4 bb = *(const float4*)(b2 + ocol);
        #pragma unroll
        for (int mi = 0; mi < 2; ++mi) {
            int tok = tok0 + mi * 16 + ln;
            const float* xr = (tok < ROWS ? x0 + (size_t)tok * 256
                                          : x1 + (size_t)(tok - ROWS) * 256);
            float4 rv = *(const float4*)(xr + ocol);
            float4 o;
            o.x = acc2[mi][nj][0] + bb.x + rv.x;
            o.y = acc2[mi][nj][1] + bb.y + rv.y;
            o.z = acc2[mi][nj][2] + bb.z + rv.z;
            o.w = acc2[mi][nj][3] + bb.w + rv.w;
            *(float4*)(out + (size_t)tok * 256 + ocol) = o;
        }
    }
}

// ---------------------------------------------------------------------------
extern "C" void kernel_launch(void* const* d_in, const int* in_sizes, int n_in,
                              void* d_out, int out_size, void* d_ws, size_t ws_size,
                              hipStream_t stream)
{
    const float* x0    = (const float*)d_in[0];
    const float* x1    = (const float*)d_in[1];
    const float* Wqk   = (const float*)d_in[2];
    const float* bqk   = (const float*)d_in[3];
    const float* Wv    = (const float*)d_in[4];
    const float* bv    = (const float*)d_in[5];
    const float* Wp    = (const float*)d_in[6];
    const float* bp    = (const float*)d_in[7];
    const float* W1    = (const float*)d_in[8];
    const float* b1    = (const float*)d_in[9];
    const float* gamma = (const float*)d_in[10];
    const float* beta  = (const float*)d_in[11];
    const float* W2    = (const float*)d_in[12];
    const float* b2    = (const float*)d_in[13];
    float* out = (float*)d_out;

    char* ws = (char*)d_ws;
    const size_t MB = 1024 * 1024;
    short* qkb  = (short*)ws;                    // [0,8)
    short* vtb  = (short*)(ws + 8  * MB);        // [8,16)
    short* pO0  = (short*)(ws + 16 * MB);        // [16,24)
    short* pO1  = (short*)(ws + 24 * MB);        // [24,32) (vbuf before attn)
    short* vbuf = pO1;
    float* l0   = (float*)(ws + 32 * MB);
    float* l1   = l0 + 16384;
    float* bc   = l1 + 16384;
    short* wq   = (short*)(bc + 512);
    short* wv   = wq + 65536;
    short* w1c  = wv + 65536;                    // [512,512]
    short* w2   = w1c + 262144;                  // [256,512]

    prep<<<1026, 256, 0, stream>>>(Wqk, Wv, Wp, W1, W2, bp, b1,
                                   wq, wv, w1c, w2, bc);
    gemm_qkv<<<dim3(4, 256), 256, 0, stream>>>(x0, x1, wq, wv, bqk, bv, qkb, vbuf);
    vtrans<<<dim3(32, 32), 256, 0, stream>>>(vbuf, vtb);
    attn8<<<dim3(16, 16, 4), 128, 0, stream>>>(qkb, vtb, pO0, pO1, l0, l1);
    mlp_fused<<<512, 256, 0, stream>>>(x0, x1, pO0, pO1, l0, l1, w1c, w2, bc,
                                       gamma, beta, b2, out);
}